// Round 1
// baseline (1936.643 us; speedup 1.0000x reference)
//
#include <hip/hip_runtime.h>
#include <math.h>

// PinSageConv fused baseline (f32, no MFMA yet).
// Stage A: h_nb gather -> (T,D)@(D,H) per node -> leaky -> weighted mean.
// Stage B: [h_nodeset | h_agg] @ W^T -> leaky -> L2 row-normalize.
// 2 nodes per 256-thread WG to halve Q_w/W_w L2 streaming traffic.

constexpr float NEG_SLOPE = 0.01f;
constexpr int T_NB   = 16;
constexpr int D_DIM  = 256;
constexpr int H_DIM  = 256;
constexpr int O_DIM  = 256;
constexpr int K_DIM  = D_DIM + H_DIM;  // 512
constexpr int G_NODES = 2;             // nodes per workgroup
constexpr int BLOCK  = 256;

__global__ __launch_bounds__(BLOCK)
void pinsage_fused(const float* __restrict__ h,
                   const int*   __restrict__ nodeset,
                   const int*   __restrict__ nb_nodes,
                   const float* __restrict__ nb_weights,
                   const float* __restrict__ Qw,
                   const float* __restrict__ Qb,
                   const float* __restrict__ Ww,
                   const float* __restrict__ Wb,
                   float*       __restrict__ out,
                   int N)
{
    __shared__ float s_h[G_NODES][T_NB][D_DIM];   // 32 KB: gathered neighbor rows
    __shared__ float s_cat[G_NODES][K_DIM];       // 4 KB: [h_nodeset | h_agg]
    __shared__ float s_w[G_NODES][T_NB];
    __shared__ float s_red[G_NODES][BLOCK / 64];

    const int tid = threadIdx.x;
    const int n0  = blockIdx.x * G_NODES;

    // ---- gather phase ----
    if (tid < G_NODES * T_NB) {
        int g = tid / T_NB, t = tid % T_NB;
        s_w[g][t] = (n0 + g < N) ? nb_weights[(n0 + g) * T_NB + t] : 0.f;
    }
    for (int g = 0; g < G_NODES; ++g) {
        int n = n0 + g;
        if (n >= N) break;
        #pragma unroll
        for (int t = 0; t < T_NB; ++t) {
            // idx < 500000, *256 fits int32 comfortably
            int idx = nb_nodes[n * T_NB + t];
            s_h[g][t][tid] = h[idx * D_DIM + tid];   // coalesced 1KB row
        }
        int idx0 = nodeset[n];
        s_cat[g][tid] = h[idx0 * D_DIM + tid];
    }
    __syncthreads();

    // ---- stage A: thread owns H-channel c = tid ----
    float acc[G_NODES][T_NB];
    #pragma unroll
    for (int g = 0; g < G_NODES; ++g)
        #pragma unroll
        for (int t = 0; t < T_NB; ++t) acc[g][t] = 0.f;

    const float4* qrow = reinterpret_cast<const float4*>(Qw + tid * D_DIM);
    for (int d4 = 0; d4 < D_DIM / 4; ++d4) {
        float4 q = qrow[d4];                    // per-lane row, L1-line reused 8x
        #pragma unroll
        for (int t = 0; t < T_NB; ++t) {
            #pragma unroll
            for (int g = 0; g < G_NODES; ++g) {
                // broadcast ds_read_b128 (all lanes same address): conflict-free
                float4 hv = *reinterpret_cast<const float4*>(&s_h[g][t][d4 * 4]);
                acc[g][t] += q.x * hv.x;
                acc[g][t] += q.y * hv.y;
                acc[g][t] += q.z * hv.z;
                acc[g][t] += q.w * hv.w;
            }
        }
    }

    float qb = Qb[tid];
    #pragma unroll
    for (int g = 0; g < G_NODES; ++g) {
        float wsum = 0.f;
        #pragma unroll
        for (int t = 0; t < T_NB; ++t) wsum += s_w[g][t];
        float wdiv = (wsum == 0.f) ? 1.f : wsum;   // _safediv
        float agg = 0.f;
        #pragma unroll
        for (int t = 0; t < T_NB; ++t) {
            float v = acc[g][t] + qb;
            v = (v > 0.f) ? v : NEG_SLOPE * v;     // leaky_relu
            agg += s_w[g][t] * v;
        }
        s_cat[g][D_DIM + tid] = agg / wdiv;
    }
    __syncthreads();

    // ---- stage B: thread owns O-channel o = tid ----
    const float4* wrow = reinterpret_cast<const float4*>(Ww + tid * K_DIM);
    float wb = Wb[tid];
    float acc2[G_NODES];
    #pragma unroll
    for (int g = 0; g < G_NODES; ++g) acc2[g] = wb;

    for (int k4 = 0; k4 < K_DIM / 4; ++k4) {
        float4 w = wrow[k4];
        #pragma unroll
        for (int g = 0; g < G_NODES; ++g) {
            float4 c = *reinterpret_cast<const float4*>(&s_cat[g][k4 * 4]);
            acc2[g] += w.x * c.x;
            acc2[g] += w.y * c.y;
            acc2[g] += w.z * c.z;
            acc2[g] += w.w * c.w;
        }
    }

    #pragma unroll
    for (int g = 0; g < G_NODES; ++g) {
        float v = acc2[g];
        acc2[g] = (v > 0.f) ? v : NEG_SLOPE * v;
        float sq = acc2[g] * acc2[g];
        #pragma unroll
        for (int off = 32; off > 0; off >>= 1) sq += __shfl_down(sq, off); // wave64
        if ((tid & 63) == 0) s_red[g][tid >> 6] = sq;
    }
    __syncthreads();

    #pragma unroll
    for (int g = 0; g < G_NODES; ++g) {
        int n = n0 + g;
        if (n >= N) break;
        float nrm = sqrtf(s_red[g][0] + s_red[g][1] + s_red[g][2] + s_red[g][3]);
        if (nrm == 0.f) nrm = 1.f;                 // _safediv
        out[n * O_DIM + tid] = acc2[g] / nrm;
    }
}

extern "C" void kernel_launch(void* const* d_in, const int* in_sizes, int n_in,
                              void* d_out, int out_size, void* d_ws, size_t ws_size,
                              hipStream_t stream)
{
    const float* h          = (const float*)d_in[0];
    const int*   nodeset    = (const int*)  d_in[1];
    const int*   nb_nodes   = (const int*)  d_in[2];
    const float* nb_weights = (const float*)d_in[3];
    const float* Qw         = (const float*)d_in[4];
    const float* Qb         = (const float*)d_in[5];
    const float* Ww         = (const float*)d_in[6];
    const float* Wb         = (const float*)d_in[7];
    float*       out        = (float*)d_out;

    int N = in_sizes[1];                       // nodeset count = 32768
    int grid = (N + G_NODES - 1) / G_NODES;    // 16384 WGs
    pinsage_fused<<<grid, BLOCK, 0, stream>>>(h, nodeset, nb_nodes, nb_weights,
                                              Qw, Qb, Ww, Wb, out, N);
}

// Round 2
// 269.661 us; speedup vs baseline: 7.1818x; 7.1818x over previous
//
#include <hip/hip_runtime.h>
#include <hip/hip_bf16.h>
#include <math.h>

// PinSageConv MFMA version.
// Stage A: per node, (T=16 x D=256) @ Q_w^T (256x256) via mfma_f32_16x16x32_bf16.
//          A fragments gathered DIRECTLY from h (no LDS staging): lane l owns
//          neighbor t = l&15, k-chunk (l>>4)*8.
// Stage B: 16 nodes/WG -> (16 x 512) @ W_w^T (512x256) MFMA, via swizzled LDS s_cat.
// Weights pre-converted to bf16 into d_ws by a tiny pre-kernel.

typedef __attribute__((ext_vector_type(8))) short bf16x8;
typedef __attribute__((ext_vector_type(4))) float f32x4;

constexpr float NEG_SLOPE = 0.01f;
constexpr int T_NB  = 16;
constexpr int D_DIM = 256;
constexpr int H_DIM = 256;
constexpr int O_DIM = 256;
constexpr int K2    = 512;          // D + H
constexpr int WAVES = 4;
constexpr int NPW   = 4;            // nodes per wave
constexpr int NPB   = WAVES * NPW;  // 16 nodes per block
constexpr int BLOCK = 256;

__device__ __forceinline__ short f2bf(float x) {
    __hip_bfloat16 b = __float2bfloat16(x);   // RNE; compiler emits cvt_pk pairs (m240)
    return *reinterpret_cast<short*>(&b);
}

__device__ __forceinline__ bf16x8 pack2(f32x4 a, f32x4 b) {
    bf16x8 o;
    o[0] = f2bf(a.x); o[1] = f2bf(a.y); o[2] = f2bf(a.z); o[3] = f2bf(a.w);
    o[4] = f2bf(b.x); o[5] = f2bf(b.y); o[6] = f2bf(b.z); o[7] = f2bf(b.w);
    return o;
}

// swizzled LDS byte offset for s_cat: row-major [16][512] bf16, XOR bits 4-6 by row
__device__ __forceinline__ unsigned swz(int row, int colbyte) {
    return (unsigned)(row * 1024 + colbyte) ^ ((unsigned)(row & 7) << 4);
}

__global__ void cvt_weights(const float* __restrict__ Qw,
                            const float* __restrict__ Ww,
                            ushort* __restrict__ dst) {
    int i = blockIdx.x * blockDim.x + threadIdx.x;
    constexpr int NQ = H_DIM * D_DIM;            // 65536
    constexpr int NT = NQ + O_DIM * K2;          // 196608
    if (i < NT) {
        float v = (i < NQ) ? Qw[i] : Ww[i - NQ];
        dst[i] = (ushort)f2bf(v);
    }
}

template<bool WPRE>
__global__ __launch_bounds__(BLOCK, 2)
void pinsage_mfma(const float* __restrict__ h,
                  const int*   __restrict__ nodeset,
                  const int*   __restrict__ nb_nodes,
                  const float* __restrict__ nb_w,
                  const float* __restrict__ Qw,
                  const float* __restrict__ Qb,
                  const float* __restrict__ Ww,
                  const float* __restrict__ Wb,
                  const ushort* __restrict__ Qbf,
                  const ushort* __restrict__ Wbf,
                  float* __restrict__ out, int N)
{
    __shared__ ushort s_cat[NPB * K2];     // 16 KB, swizzled
    __shared__ float  s_part[WAVES][NPB];
    __shared__ float  s_ninv[NPB];

    const int tid  = threadIdx.x;
    const int lane = tid & 63;
    const int wid  = tid >> 6;
    const int lrow = lane & 15;   // MFMA row (A) / col (B,D)
    const int lk   = lane >> 4;   // k-group 0..3
    const int n0   = blockIdx.x * NPB;

    // ---- stage 0: gather h[nodeset] rows -> s_cat cols [0,256) (bf16, swizzled)
    {
        int r = tid >> 4;                  // node row 0..15
        int j = tid & 15;                  // 16-float chunk 0..15
        int n = n0 + r;
        int idx = (n < N) ? nodeset[n] : 0;
        const float* src = h + (long)idx * D_DIM + j * 16;
        f32x4 v0 = *(const f32x4*)(src + 0);
        f32x4 v1 = *(const f32x4*)(src + 4);
        f32x4 v2 = *(const f32x4*)(src + 8);
        f32x4 v3 = *(const f32x4*)(src + 12);
        bf16x8 p0 = pack2(v0, v1), p1 = pack2(v2, v3);
        *(bf16x8*)((char*)s_cat + swz(r, j * 32))      = p0;
        *(bf16x8*)((char*)s_cat + swz(r, j * 32 + 16)) = p1;
    }

    // ---- stage A setup: per-wave nodes, neighbor idx + normalized weights
    int   aidx[NPW];
    float wn[NPW][4];
    #pragma unroll
    for (int g = 0; g < NPW; ++g) {
        int n  = n0 + wid * NPW + g;
        int nc = (n < N) ? n : 0;
        aidx[g] = nb_nodes[nc * T_NB + lrow];      // lane owns neighbor t = lrow
        f32x4 w4 = *(const f32x4*)(nb_w + nc * T_NB + lk * 4);
        float wsum = w4.x + w4.y + w4.z + w4.w;
        wsum += __shfl_xor(wsum, 16);
        wsum += __shfl_xor(wsum, 32);
        float inv = (wsum == 0.f) ? 1.f : 1.f / wsum;   // _safediv
        if (n >= N) inv = 0.f;
        wn[g][0] = w4.x * inv; wn[g][1] = w4.y * inv;
        wn[g][2] = w4.z * inv; wn[g][3] = w4.w * inv;
    }

    // ---- A fragments: direct register gather from h (f32 -> bf16)
    bf16x8 aF[NPW][8];
    #pragma unroll
    for (int g = 0; g < NPW; ++g) {
        const float* base = h + (long)aidx[g] * D_DIM + lk * 8;
        #pragma unroll
        for (int ks = 0; ks < 8; ++ks) {
            f32x4 u0 = *(const f32x4*)(base + ks * 32 + 0);
            f32x4 u1 = *(const f32x4*)(base + ks * 32 + 4);
            aF[g][ks] = pack2(u0, u1);
        }
    }

    // ---- stage A: 16 n-tiles of H, 8 k-steps each, 4 nodes deep
    for (int nt = 0; nt < 16; ++nt) {
        bf16x8 bF[8];
        if (WPRE) {
            const ushort* bb = Qbf + (nt * 16 + lrow) * D_DIM + lk * 8;
            #pragma unroll
            for (int ks = 0; ks < 8; ++ks)
                bF[ks] = *(const bf16x8*)(bb + ks * 32);
        } else {
            const float* bb = Qw + (nt * 16 + lrow) * D_DIM + lk * 8;
            #pragma unroll
            for (int ks = 0; ks < 8; ++ks) {
                f32x4 u0 = *(const f32x4*)(bb + ks * 32 + 0);
                f32x4 u1 = *(const f32x4*)(bb + ks * 32 + 4);
                bF[ks] = pack2(u0, u1);
            }
        }
        f32x4 acc[NPW];
        #pragma unroll
        for (int g = 0; g < NPW; ++g) acc[g] = (f32x4){0.f, 0.f, 0.f, 0.f};
        #pragma unroll
        for (int g = 0; g < NPW; ++g)
            #pragma unroll
            for (int ks = 0; ks < 8; ++ks)
                acc[g] = __builtin_amdgcn_mfma_f32_16x16x32_bf16(aF[g][ks], bF[ks], acc[g], 0, 0, 0);

        // epilogue: +Qb, leaky, weighted mean over T (rows), write h_agg cols
        float qb = Qb[nt * 16 + lrow];
        #pragma unroll
        for (int g = 0; g < NPW; ++g) {
            float p = 0.f;
            #pragma unroll
            for (int r = 0; r < 4; ++r) {
                float v = acc[g][r] + qb;          // row t = lk*4 + r, col = lrow
                v = (v > 0.f) ? v : v * NEG_SLOPE;
                p += wn[g][r] * v;
            }
            p += __shfl_xor(p, 16);
            p += __shfl_xor(p, 32);
            if (lane < 16) {
                int node = wid * NPW + g;
                *(ushort*)((char*)s_cat + swz(node, (D_DIM + nt * 16 + lane) * 2)) =
                    (ushort)f2bf(p);
            }
        }
    }
    __syncthreads();

    // ---- stage B: (16 nodes x 512) @ W^T. Wave owns 64 output cols.
    bf16x8 a2[16];
    #pragma unroll
    for (int ks = 0; ks < 16; ++ks)
        a2[ks] = *(const bf16x8*)((char*)s_cat + swz(lrow, ks * 64 + lk * 16));

    float vout[4][4];
    float sq[4] = {0.f, 0.f, 0.f, 0.f};
    #pragma unroll
    for (int ot = 0; ot < 4; ++ot) {
        int ocol = wid * 64 + ot * 16 + lrow;
        f32x4 acc = (f32x4){0.f, 0.f, 0.f, 0.f};
        if (WPRE) {
            const ushort* bb = Wbf + ocol * K2 + lk * 8;
            #pragma unroll
            for (int ks = 0; ks < 16; ++ks) {
                bf16x8 bF = *(const bf16x8*)(bb + ks * 32);
                acc = __builtin_amdgcn_mfma_f32_16x16x32_bf16(a2[ks], bF, acc, 0, 0, 0);
            }
        } else {
            const float* bb = Ww + ocol * K2 + lk * 8;
            #pragma unroll
            for (int ks = 0; ks < 16; ++ks) {
                f32x4 u0 = *(const f32x4*)(bb + ks * 32 + 0);
                f32x4 u1 = *(const f32x4*)(bb + ks * 32 + 4);
                bf16x8 bF = pack2(u0, u1);
                acc = __builtin_amdgcn_mfma_f32_16x16x32_bf16(a2[ks], bF, acc, 0, 0, 0);
            }
        }
        float wb = Wb[ocol];
        #pragma unroll
        for (int r = 0; r < 4; ++r) {
            float v = acc[r] + wb;                 // row node = lk*4+r, col = ocol
            v = (v > 0.f) ? v : v * NEG_SLOPE;
            vout[ot][r] = v;
            sq[r] += v * v;
        }
    }
    // reduce squared sums over the 16 cols held by lanes sharing lk
    #pragma unroll
    for (int r = 0; r < 4; ++r) {
        sq[r] += __shfl_xor(sq[r], 1);
        sq[r] += __shfl_xor(sq[r], 2);
        sq[r] += __shfl_xor(sq[r], 4);
        sq[r] += __shfl_xor(sq[r], 8);
    }
    if (lrow == 0) {
        #pragma unroll
        for (int r = 0; r < 4; ++r) s_part[wid][lk * 4 + r] = sq[r];
    }
    __syncthreads();
    if (tid < NPB) {
        float s = s_part[0][tid] + s_part[1][tid] + s_part[2][tid] + s_part[3][tid];
        s_ninv[tid] = (s == 0.f) ? 1.f : 1.f / sqrtf(s);   // _safediv on norm
    }
    __syncthreads();

    #pragma unroll
    for (int r = 0; r < 4; ++r) {
        int node = lk * 4 + r;
        int n = n0 + node;
        if (n < N) {
            float inv = s_ninv[node];
            #pragma unroll
            for (int ot = 0; ot < 4; ++ot)
                out[(long)n * O_DIM + wid * 64 + ot * 16 + lrow] = vout[ot][r] * inv;
        }
    }
}

extern "C" void kernel_launch(void* const* d_in, const int* in_sizes, int n_in,
                              void* d_out, int out_size, void* d_ws, size_t ws_size,
                              hipStream_t stream)
{
    const float* h        = (const float*)d_in[0];
    const int*   nodeset  = (const int*)  d_in[1];
    const int*   nb_nodes = (const int*)  d_in[2];
    const float* nb_w     = (const float*)d_in[3];
    const float* Qw       = (const float*)d_in[4];
    const float* Qb       = (const float*)d_in[5];
    const float* Ww       = (const float*)d_in[6];
    const float* Wb       = (const float*)d_in[7];
    float*       out      = (float*)d_out;

    int N = in_sizes[1];
    int grid = (N + NPB - 1) / NPB;

    constexpr size_t WBYTES = (size_t)(H_DIM * D_DIM + O_DIM * K2) * sizeof(ushort);
    bool wpre = (d_ws != nullptr) && (ws_size >= WBYTES);

    if (wpre) {
        ushort* wbuf = (ushort*)d_ws;
        cvt_weights<<<(H_DIM * D_DIM + O_DIM * K2 + 255) / 256, 256, 0, stream>>>(Qw, Ww, wbuf);
        pinsage_mfma<true><<<grid, BLOCK, 0, stream>>>(
            h, nodeset, nb_nodes, nb_w, Qw, Qb, Ww, Wb,
            wbuf, wbuf + H_DIM * D_DIM, out, N);
    } else {
        pinsage_mfma<false><<<grid, BLOCK, 0, stream>>>(
            h, nodeset, nb_nodes, nb_w, Qw, Qb, Ww, Wb,
            nullptr, nullptr, out, N);
    }
}

// Round 3
// 262.365 us; speedup vs baseline: 7.3815x; 1.0278x over previous
//
#include <hip/hip_runtime.h>
#include <hip/hip_bf16.h>
#include <math.h>

// PinSageConv split version.
// K1: neighbor gather (coalesced, dbuf LDS, bf16) + stage-A einsum with
//     Q-fragments persistent in registers (wave owns 32 H-cols) -> agg (f32, ws).
// K2: [h[nodeset] | agg] @ W^T + leaky + L2-normalize (R2 stage-B structure).
// Weights pre-converted to bf16 in ws. Monolithic R2 kernel kept as fallback.

typedef __attribute__((ext_vector_type(8))) short bf16x8;
typedef __attribute__((ext_vector_type(4))) float f32x4;

constexpr float NEG_SLOPE = 0.01f;
constexpr int T_NB  = 16;
constexpr int D_DIM = 256;
constexpr int H_DIM = 256;
constexpr int O_DIM = 256;
constexpr int K2    = 512;

__device__ __forceinline__ short f2bf(float x) {
    __hip_bfloat16 b = __float2bfloat16(x);
    return *reinterpret_cast<short*>(&b);
}
__device__ __forceinline__ bf16x8 pack2(f32x4 a, f32x4 b) {
    bf16x8 o;
    o[0] = f2bf(a.x); o[1] = f2bf(a.y); o[2] = f2bf(a.z); o[3] = f2bf(a.w);
    o[4] = f2bf(b.x); o[5] = f2bf(b.y); o[6] = f2bf(b.z); o[7] = f2bf(b.w);
    return o;
}

__global__ void cvt_weights(const float* __restrict__ Qw,
                            const float* __restrict__ Ww,
                            ushort* __restrict__ dst) {
    int i = blockIdx.x * blockDim.x + threadIdx.x;
    constexpr int NQ = H_DIM * D_DIM;
    constexpr int NT = NQ + O_DIM * K2;
    if (i < NT) {
        float v = (i < NQ) ? Qw[i] : Ww[i - NQ];
        dst[i] = (ushort)f2bf(v);
    }
}

// ================= Kernel 1: gather + stage A =================
constexpr int BLK1 = 512;   // 8 waves
constexpr int NPB1 = 16;    // nodes per block (8 batches of 2)

__global__ __launch_bounds__(BLK1, 4)
void pinsage_k1(const float* __restrict__ h,
                const int*   __restrict__ nb_nodes,
                const float* __restrict__ nb_w,
                const ushort* __restrict__ Qbf,
                const float* __restrict__ Qb,
                float* __restrict__ agg,   // [N][256] f32
                int N)
{
    // [buf][(g*16+r)*512B row, XOR-swizzled within row]
    __shared__ ushort s_a[2][2 * T_NB * D_DIM];   // 2 x 16 KB

    const int tid  = threadIdx.x;
    const int lane = tid & 63;
    const int wid  = tid >> 6;      // 0..7
    const int lrow = lane & 15;
    const int lk   = lane >> 4;
    const int n0   = blockIdx.x * NPB1;

    // persistent B fragments: wave owns H-col tiles nt = wid*2 + tt
    bf16x8 bF[2][8];
    float  qb[2];
    #pragma unroll
    for (int tt = 0; tt < 2; ++tt) {
        int nt = wid * 2 + tt;
        const char* base = (const char*)Qbf + (nt * 16 + lrow) * 512 + lk * 16;
        #pragma unroll
        for (int ks = 0; ks < 8; ++ks)
            bF[tt][ks] = *(const bf16x8*)(base + ks * 64);
        qb[tt] = Qb[nt * 16 + lrow];
    }

    // staging role: thread covers row sR (0..31) f32 segment sj (64 B)
    const int sR = tid >> 4;
    const int sg = sR >> 4;          // node within pair
    const int sr = sR & 15;          // neighbor index
    const int sj = tid & 15;

    f32x4 u0, u1, u2, u3;
    {   // prologue: issue loads for batch 0
        int n  = n0 + sg;
        int nc = (n < N) ? n : N - 1;
        int idx = nb_nodes[nc * T_NB + sr];
        const f32x4* src = (const f32x4*)(h + (long)idx * D_DIM + sj * 16);
        u0 = src[0]; u1 = src[1]; u2 = src[2]; u3 = src[3];
    }

    for (int b = 0; b < 8; ++b) {
        const int buf = b & 1;
        {   // write staged rows (bf16, swizzled)
            char* dst = (char*)s_a[buf] + (sg * 16 + sr) * 512;
            unsigned x = ((unsigned)(sr & 7)) << 4;
            *(bf16x8*)(dst + ((sj * 32     ) ^ x)) = pack2(u0, u1);
            *(bf16x8*)(dst + ((sj * 32 + 16) ^ x)) = pack2(u2, u3);
        }
        if (b < 7) {  // issue next batch's loads (in flight during compute)
            int n  = n0 + (b + 1) * 2 + sg;
            int nc = (n < N) ? n : N - 1;
            int idx = nb_nodes[nc * T_NB + sr];
            const f32x4* src = (const f32x4*)(h + (long)idx * D_DIM + sj * 16);
            u0 = src[0]; u1 = src[1]; u2 = src[2]; u3 = src[3];
        }
        __syncthreads();   // staging[buf] visible to all waves

        #pragma unroll
        for (int g = 0; g < 2; ++g) {
            int n  = n0 + b * 2 + g;
            int nc = (n < N) ? n : N - 1;
            // normalized weights for rows t = lk*4 + r
            f32x4 w4 = *(const f32x4*)(nb_w + (long)nc * T_NB + lk * 4);
            float wsum = w4.x + w4.y + w4.z + w4.w;
            wsum += __shfl_xor(wsum, 16);
            wsum += __shfl_xor(wsum, 32);
            float inv = (wsum == 0.f) ? 1.f : 1.f / wsum;
            float wn0 = w4.x * inv, wn1 = w4.y * inv,
                  wn2 = w4.z * inv, wn3 = w4.w * inv;

            f32x4 acc0 = {0.f,0.f,0.f,0.f}, acc1 = {0.f,0.f,0.f,0.f};
            const char* ab = (const char*)s_a[buf] + (g * 16 + lrow) * 512;
            unsigned x = ((unsigned)(lrow & 7)) << 4;
            #pragma unroll
            for (int ks = 0; ks < 8; ++ks) {
                bf16x8 aF = *(const bf16x8*)(ab + (((unsigned)(ks * 64 + lk * 16)) ^ x));
                acc0 = __builtin_amdgcn_mfma_f32_16x16x32_bf16(aF, bF[0][ks], acc0, 0, 0, 0);
                acc1 = __builtin_amdgcn_mfma_f32_16x16x32_bf16(aF, bF[1][ks], acc1, 0, 0, 0);
            }
            #pragma unroll
            for (int tt = 0; tt < 2; ++tt) {
                f32x4 acc = tt ? acc1 : acc0;
                float p = 0.f, v;
                v = acc[0] + qb[tt]; v = (v > 0.f) ? v : v * NEG_SLOPE; p += wn0 * v;
                v = acc[1] + qb[tt]; v = (v > 0.f) ? v : v * NEG_SLOPE; p += wn1 * v;
                v = acc[2] + qb[tt]; v = (v > 0.f) ? v : v * NEG_SLOPE; p += wn2 * v;
                v = acc[3] + qb[tt]; v = (v > 0.f) ? v : v * NEG_SLOPE; p += wn3 * v;
                p += __shfl_xor(p, 16);
                p += __shfl_xor(p, 32);
                if (n < N && lane < 16)
                    agg[(long)n * H_DIM + (wid * 2 + tt) * 16 + lane] = p;
            }
        }
        // no end barrier needed: next iteration writes the OTHER buffer, and
        // its pre-compute barrier orders it against this batch's readers.
    }
}

// ================= Kernel 2: concat GEMM + norm =================
constexpr int NPB2 = 16;

// swizzled byte offset into s_cat rows of 1024 B
__device__ __forceinline__ unsigned swz(int row, int colbyte) {
    return (unsigned)(row * 1024 + colbyte) ^ ((unsigned)(row & 7) << 4);
}

__global__ __launch_bounds__(256, 4)
void pinsage_k2(const float* __restrict__ h,
                const int*   __restrict__ nodeset,
                const float* __restrict__ agg,
                const ushort* __restrict__ Wbf,
                const float* __restrict__ Wb,
                float* __restrict__ out, int N)
{
    __shared__ ushort s_cat[NPB2 * K2];    // 16 KB swizzled
    __shared__ float  s_part[4][NPB2];
    __shared__ float  s_ninv[NPB2];

    const int tid  = threadIdx.x;
    const int lane = tid & 63;
    const int wid  = tid >> 6;
    const int lrow = lane & 15;
    const int lk   = lane >> 4;
    const int n0   = blockIdx.x * NPB2;

    {   // stage [h_nodeset | agg] -> s_cat (bf16, swizzled)
        int r = tid >> 4, j = tid & 15;
        int n  = n0 + r;
        int nc = (n < N) ? n : N - 1;
        int idx = nodeset[nc];
        const f32x4* s1 = (const f32x4*)(h + (long)idx * D_DIM + j * 16);
        f32x4 a0 = s1[0], a1 = s1[1], a2_ = s1[2], a3 = s1[3];
        const f32x4* s2 = (const f32x4*)(agg + (long)nc * H_DIM + j * 16);
        f32x4 b0 = s2[0], b1 = s2[1], b2 = s2[2], b3 = s2[3];
        *(bf16x8*)((char*)s_cat + swz(r, j * 32))            = pack2(a0, a1);
        *(bf16x8*)((char*)s_cat + swz(r, j * 32 + 16))       = pack2(a2_, a3);
        *(bf16x8*)((char*)s_cat + swz(r, 512 + j * 32))      = pack2(b0, b1);
        *(bf16x8*)((char*)s_cat + swz(r, 512 + j * 32 + 16)) = pack2(b2, b3);
    }
    __syncthreads();

    bf16x8 a2[16];
    #pragma unroll
    for (int ks = 0; ks < 16; ++ks)
        a2[ks] = *(const bf16x8*)((char*)s_cat + swz(lrow, ks * 64 + lk * 16));

    float vout[4][4];
    float sq[4] = {0.f, 0.f, 0.f, 0.f};
    #pragma unroll
    for (int ot = 0; ot < 4; ++ot) {
        int ocol = wid * 64 + ot * 16 + lrow;
        f32x4 acc = {0.f,0.f,0.f,0.f};
        const ushort* bb = Wbf + ocol * K2 + lk * 8;
        #pragma unroll
        for (int ks = 0; ks < 16; ++ks) {
            bf16x8 bF = *(const bf16x8*)(bb + ks * 32);
            acc = __builtin_amdgcn_mfma_f32_16x16x32_bf16(a2[ks], bF, acc, 0, 0, 0);
        }
        float wb = Wb[ocol];
        #pragma unroll
        for (int r = 0; r < 4; ++r) {
            float v = acc[r] + wb;
            v = (v > 0.f) ? v : v * NEG_SLOPE;
            vout[ot][r] = v;
            sq[r] += v * v;
        }
    }
    #pragma unroll
    for (int r = 0; r < 4; ++r) {
        sq[r] += __shfl_xor(sq[r], 1);
        sq[r] += __shfl_xor(sq[r], 2);
        sq[r] += __shfl_xor(sq[r], 4);
        sq[r] += __shfl_xor(sq[r], 8);
    }
    if (lrow == 0) {
        #pragma unroll
        for (int r = 0; r < 4; ++r) s_part[wid][lk * 4 + r] = sq[r];
    }
    __syncthreads();
    if (tid < NPB2) {
        float s = s_part[0][tid] + s_part[1][tid] + s_part[2][tid] + s_part[3][tid];
        s_ninv[tid] = (s == 0.f) ? 1.f : 1.f / sqrtf(s);
    }
    __syncthreads();

    #pragma unroll
    for (int r = 0; r < 4; ++r) {
        int node = lk * 4 + r;
        int n = n0 + node;
        if (n < N) {
            float inv = s_ninv[node];
            #pragma unroll
            for (int ot = 0; ot < 4; ++ot)
                out[(long)n * O_DIM + wid * 64 + ot * 16 + lrow] = vout[ot][r] * inv;
        }
    }
}

// ================= Fallback: R2 monolithic (proven) =================
constexpr int WAVES = 4;
constexpr int NPW   = 4;
constexpr int NPB   = WAVES * NPW;
constexpr int BLOCK = 256;

template<bool WPRE>
__global__ __launch_bounds__(BLOCK, 2)
void pinsage_mfma(const float* __restrict__ h,
                  const int*   __restrict__ nodeset,
                  const int*   __restrict__ nb_nodes,
                  const float* __restrict__ nb_w,
                  const float* __restrict__ Qw,
                  const float* __restrict__ Qb,
                  const float* __restrict__ Ww,
                  const float* __restrict__ Wb,
                  const ushort* __restrict__ Qbf,
                  const ushort* __restrict__ Wbf,
                  float* __restrict__ out, int N)
{
    __shared__ ushort s_cat[NPB * K2];
    __shared__ float  s_part[WAVES][NPB];
    __shared__ float  s_ninv[NPB];

    const int tid  = threadIdx.x;
    const int lane = tid & 63;
    const int wid  = tid >> 6;
    const int lrow = lane & 15;
    const int lk   = lane >> 4;
    const int n0   = blockIdx.x * NPB;

    {
        int r = tid >> 4, j = tid & 15;
        int n = n0 + r;
        int idx = (n < N) ? nodeset[n] : 0;
        const float* src = h + (long)idx * D_DIM + j * 16;
        f32x4 v0 = *(const f32x4*)(src + 0);
        f32x4 v1 = *(const f32x4*)(src + 4);
        f32x4 v2 = *(const f32x4*)(src + 8);
        f32x4 v3 = *(const f32x4*)(src + 12);
        *(bf16x8*)((char*)s_cat + swz(r, j * 32))      = pack2(v0, v1);
        *(bf16x8*)((char*)s_cat + swz(r, j * 32 + 16)) = pack2(v2, v3);
    }

    int   aidx[NPW];
    float wn[NPW][4];
    #pragma unroll
    for (int g = 0; g < NPW; ++g) {
        int n  = n0 + wid * NPW + g;
        int nc = (n < N) ? n : 0;
        aidx[g] = nb_nodes[nc * T_NB + lrow];
        f32x4 w4 = *(const f32x4*)(nb_w + nc * T_NB + lk * 4);
        float wsum = w4.x + w4.y + w4.z + w4.w;
        wsum += __shfl_xor(wsum, 16);
        wsum += __shfl_xor(wsum, 32);
        float inv = (wsum == 0.f) ? 1.f : 1.f / wsum;
        if (n >= N) inv = 0.f;
        wn[g][0] = w4.x * inv; wn[g][1] = w4.y * inv;
        wn[g][2] = w4.z * inv; wn[g][3] = w4.w * inv;
    }

    bf16x8 aF[NPW][8];
    #pragma unroll
    for (int g = 0; g < NPW; ++g) {
        const float* base = h + (long)aidx[g] * D_DIM + lk * 8;
        #pragma unroll
        for (int ks = 0; ks < 8; ++ks) {
            f32x4 t0 = *(const f32x4*)(base + ks * 32 + 0);
            f32x4 t1 = *(const f32x4*)(base + ks * 32 + 4);
            aF[g][ks] = pack2(t0, t1);
        }
    }

    for (int nt = 0; nt < 16; ++nt) {
        bf16x8 bF[8];
        if (WPRE) {
            const ushort* bb = Qbf + (nt * 16 + lrow) * D_DIM + lk * 8;
            #pragma unroll
            for (int ks = 0; ks < 8; ++ks)
                bF[ks] = *(const bf16x8*)(bb + ks * 32);
        } else {
            const float* bb = Qw + (nt * 16 + lrow) * D_DIM + lk * 8;
            #pragma unroll
            for (int ks = 0; ks < 8; ++ks) {
                f32x4 t0 = *(const f32x4*)(bb + ks * 32 + 0);
                f32x4 t1 = *(const f32x4*)(bb + ks * 32 + 4);
                bF[ks] = pack2(t0, t1);
            }
        }
        f32x4 acc[NPW];
        #pragma unroll
        for (int g = 0; g < NPW; ++g) acc[g] = (f32x4){0.f,0.f,0.f,0.f};
        #pragma unroll
        for (int g = 0; g < NPW; ++g)
            #pragma unroll
            for (int ks = 0; ks < 8; ++ks)
                acc[g] = __builtin_amdgcn_mfma_f32_16x16x32_bf16(aF[g][ks], bF[ks], acc[g], 0, 0, 0);

        float qb = Qb[nt * 16 + lrow];
        #pragma unroll
        for (int g = 0; g < NPW; ++g) {
            float p = 0.f;
            #pragma unroll
            for (int r = 0; r < 4; ++r) {
                float v = acc[g][r] + qb;
                v = (v > 0.f) ? v : v * NEG_SLOPE;
                p += wn[g][r] * v;
            }
            p += __shfl_xor(p, 16);
            p += __shfl_xor(p, 32);
            if (lane < 16) {
                int node = wid * NPW + g;
                *(ushort*)((char*)s_cat + swz(node, (D_DIM + nt * 16 + lane) * 2)) =
                    (ushort)f2bf(p);
            }
        }
    }
    __syncthreads();

    bf16x8 a2[16];
    #pragma unroll
    for (int ks = 0; ks < 16; ++ks)
        a2[ks] = *(const bf16x8*)((char*)s_cat + swz(lrow, ks * 64 + lk * 16));

    float vout[4][4];
    float sq[4] = {0.f, 0.f, 0.f, 0.f};
    #pragma unroll
    for (int ot = 0; ot < 4; ++ot) {
        int ocol = wid * 64 + ot * 16 + lrow;
        f32x4 acc = {0.f,0.f,0.f,0.f};
        if (WPRE) {
            const ushort* bb = Wbf + ocol * K2 + lk * 8;
            #pragma unroll
            for (int ks = 0; ks < 16; ++ks) {
                bf16x8 bF = *(const bf16x8*)(bb + ks * 32);
                acc = __builtin_amdgcn_mfma_f32_16x16x32_bf16(a2[ks], bF, acc, 0, 0, 0);
            }
        } else {
            const float* bb = Ww + ocol * K2 + lk * 8;
            #pragma unroll
            for (int ks = 0; ks < 16; ++ks) {
                f32x4 t0 = *(const f32x4*)(bb + ks * 32 + 0);
                f32x4 t1 = *(const f32x4*)(bb + ks * 32 + 4);
                bf16x8 bF = pack2(t0, t1);
                acc = __builtin_amdgcn_mfma_f32_16x16x32_bf16(a2[ks], bF, acc, 0, 0, 0);
            }
        }
        float wb = Wb[ocol];
        #pragma unroll
        for (int r = 0; r < 4; ++r) {
            float v = acc[r] + wb;
            v = (v > 0.f) ? v : v * NEG_SLOPE;
            vout[ot][r] = v;
            sq[r] += v * v;
        }
    }
    #pragma unroll
    for (int r = 0; r < 4; ++r) {
        sq[r] += __shfl_xor(sq[r], 1);
        sq[r] += __shfl_xor(sq[r], 2);
        sq[r] += __shfl_xor(sq[r], 4);
        sq[r] += __shfl_xor(sq[r], 8);
    }
    if (lrow == 0) {
        #pragma unroll
        for (int r = 0; r < 4; ++r) s_part[wid][lk * 4 + r] = sq[r];
    }
    __syncthreads();
    if (tid < NPB) {
        float s = s_part[0][tid] + s_part[1][tid] + s_part[2][tid] + s_part[3][tid];
        s_ninv[tid] = (s == 0.f) ? 1.f : 1.f / sqrtf(s);
    }
    __syncthreads();

    #pragma unroll
    for (int r = 0; r < 4; ++r) {
        int node = lk * 4 + r;
        int n = n0 + node;
        if (n < N) {
            float inv = s_ninv[node];
            #pragma unroll
            for (int ot = 0; ot < 4; ++ot)
                out[(long)n * O_DIM + wid * 64 + ot * 16 + lrow] = vout[ot][r] * inv;
        }
    }
}

extern "C" void kernel_launch(void* const* d_in, const int* in_sizes, int n_in,
                              void* d_out, int out_size, void* d_ws, size_t ws_size,
                              hipStream_t stream)
{
    const float* h        = (const float*)d_in[0];
    const int*   nodeset  = (const int*)  d_in[1];
    const int*   nb_nodes = (const int*)  d_in[2];
    const float* nb_w     = (const float*)d_in[3];
    const float* Qw       = (const float*)d_in[4];
    const float* Qb       = (const float*)d_in[5];
    const float* Ww       = (const float*)d_in[6];
    const float* Wb       = (const float*)d_in[7];
    float*       out      = (float*)d_out;

    int N = in_sizes[1];

    constexpr size_t WBYTES  = (size_t)(H_DIM * D_DIM + O_DIM * K2) * sizeof(ushort); // 384 KB
    const size_t AGG_BYTES   = (size_t)N * H_DIM * sizeof(float);
    const size_t SPLIT_BYTES = WBYTES + AGG_BYTES;

    if (d_ws && ws_size >= SPLIT_BYTES) {
        ushort* wbuf = (ushort*)d_ws;
        ushort* Qbf  = wbuf;
        ushort* Wbf  = wbuf + H_DIM * D_DIM;
        float*  agg  = (float*)((char*)d_ws + WBYTES);
        cvt_weights<<<(H_DIM * D_DIM + O_DIM * K2 + 255) / 256, 256, 0, stream>>>(Qw, Ww, wbuf);
        pinsage_k1<<<(N + NPB1 - 1) / NPB1, BLK1, 0, stream>>>(
            h, nb_nodes, nb_w, Qbf, Qb, agg, N);
        pinsage_k2<<<(N + NPB2 - 1) / NPB2, 256, 0, stream>>>(
            h, nodeset, agg, Wbf, Wb, out, N);
    } else if (d_ws && ws_size >= WBYTES) {
        ushort* wbuf = (ushort*)d_ws;
        cvt_weights<<<(H_DIM * D_DIM + O_DIM * K2 + 255) / 256, 256, 0, stream>>>(Qw, Ww, wbuf);
        pinsage_mfma<true><<<(N + NPB - 1) / NPB, BLOCK, 0, stream>>>(
            h, nodeset, nb_nodes, nb_w, Qw, Qb, Ww, Wb,
            wbuf, wbuf + H_DIM * D_DIM, out, N);
    } else {
        pinsage_mfma<false><<<(N + NPB - 1) / NPB, BLOCK, 0, stream>>>(
            h, nodeset, nb_nodes, nb_w, Qw, Qb, Ww, Wb,
            nullptr, nullptr, out, N);
    }
}

// Round 4
// 185.351 us; speedup vs baseline: 10.4485x; 1.4155x over previous
//
#include <hip/hip_runtime.h>
#include <hip/hip_bf16.h>
#include <math.h>

// PinSageConv R4.
// K1: per block 16 nodes; neighbor rows DMA'd global->LDS (f32, source-swizzled),
//     3-buffer pipeline, counted vmcnt (never 0 in loop), raw s_barrier.
//     Stage-A MFMA with Q register-resident (wave owns 2 col-tiles). agg -> LDS,
//     bulk coalesced store at end.
// K2: [h[nodeset] | agg] @ W^T + leaky + L2-normalize; W in chunk-transposed
//     layout so every B load is 1KB contiguous.

typedef __attribute__((ext_vector_type(8))) short bf16x8;
typedef __attribute__((ext_vector_type(4))) float f32x4;

constexpr float NEG_SLOPE = 0.01f;
constexpr int T_NB  = 16;
constexpr int D_DIM = 256;
constexpr int H_DIM = 256;
constexpr int O_DIM = 256;
constexpr int K2C   = 512;

__device__ __forceinline__ short f2bf(float x) {
    __hip_bfloat16 b = __float2bfloat16(x);
    return *reinterpret_cast<short*>(&b);
}
__device__ __forceinline__ bf16x8 pack2(f32x4 a, f32x4 b) {
    bf16x8 o;
    o[0] = f2bf(a.x); o[1] = f2bf(a.y); o[2] = f2bf(a.z); o[3] = f2bf(a.w);
    o[4] = f2bf(b.x); o[5] = f2bf(b.y); o[6] = f2bf(b.z); o[7] = f2bf(b.w);
    return o;
}

#define AS_GLOBAL __attribute__((address_space(1)))
#define AS_SHARED __attribute__((address_space(3)))
__device__ __forceinline__ void gld_lds16(const void* g, void* l) {
    __builtin_amdgcn_global_load_lds((const AS_GLOBAL unsigned int*)g,
                                     (AS_SHARED unsigned int*)l, 16, 0, 0);
}

// ---- weight conversion: Qbf plain [256][256]; Wt chunk-transposed:
// Wt[(o>>4)][c][o&15][kk], c = k>>3, kk = k&7  (ushort units)
__global__ void cvt_weights(const float* __restrict__ Qw,
                            const float* __restrict__ Ww,
                            ushort* __restrict__ qdst,
                            ushort* __restrict__ wdst) {
    int i = blockIdx.x * blockDim.x + threadIdx.x;
    if (i < H_DIM * D_DIM) qdst[i] = (ushort)f2bf(Qw[i]);
    if (i < O_DIM * K2C) {
        int o = i >> 9, k = i & 511;
        wdst[((o >> 4) * 64 + (k >> 3)) * 128 + (o & 15) * 8 + (k & 7)] =
            (ushort)f2bf(Ww[i]);
    }
}

// ================= Kernel 1 =================
constexpr int BLK1 = 512;   // 8 waves
constexpr int NPB1 = 16;    // nodes per block, 1 node per batch

__global__ __launch_bounds__(BLK1, 4)
void pinsage_k1(const float* __restrict__ h,
                const int*   __restrict__ nb_nodes,
                const float* __restrict__ nb_w,
                const ushort* __restrict__ Qbf,
                const float* __restrict__ Qb,
                float* __restrict__ agg,
                int N)
{
    __shared__ float s_stage[3][T_NB][D_DIM];  // 48 KB, source-swizzled f32
    __shared__ float s_agg[NPB1][H_DIM];       // 16 KB
    __shared__ int   s_idx[NPB1 * T_NB];
    __shared__ float s_wt[NPB1 * T_NB];
    __shared__ float s_winv[NPB1];

    const int tid  = threadIdx.x;
    const int lane = tid & 63;
    const int wid  = tid >> 6;      // 0..7
    const int lrow = lane & 15;
    const int lk   = lane >> 4;
    const int n0   = blockIdx.x * NPB1;

    // ---- prologue: all global loads besides DMA happen here ----
    if (tid < NPB1 * T_NB) {
        int n  = n0 + (tid >> 4);
        int nc = (n < N) ? n : N - 1;
        s_idx[tid] = nb_nodes[nc * T_NB + (tid & 15)];
        s_wt[tid]  = (n < N) ? nb_w[nc * T_NB + (tid & 15)] : 0.f;
    }
    __syncthreads();
    if (tid < NPB1) {
        float s = 0.f;
        #pragma unroll
        for (int t = 0; t < T_NB; ++t) s += s_wt[tid * T_NB + t];
        s_winv[tid] = (s == 0.f) ? 1.f : 1.f / s;
    }
    // B fragments: wave owns col-tiles nt = wid*2 + tt
    bf16x8 bF[2][8];
    float  qb[2];
    #pragma unroll
    for (int tt = 0; tt < 2; ++tt) {
        int nt = wid * 2 + tt;
        const ushort* bb = Qbf + (nt * 16 + lrow) * D_DIM + lk * 8;
        #pragma unroll
        for (int ks = 0; ks < 8; ++ks)
            bF[tt][ks] = *(const bf16x8*)(bb + ks * 32);
        qb[tt] = Qb[nt * 16 + lrow];
    }
    __syncthreads();   // drains prologue vmem -> vmcnt baseline = 0

    // ---- DMA issue: wave stages rows {2*wid, 2*wid+1} of node b.
    // Source chunk pre-swizzled: LDS[r][j] = global[r][j ^ 4r]  (16B chunks)
    auto issue = [&](int b) {
        #pragma unroll
        for (int rr = 0; rr < 2; ++rr) {
            int row = wid * 2 + rr;
            int idx = s_idx[b * T_NB + row];
            const float* src = h + (long)idx * D_DIM + ((lane ^ (row << 2)) << 2);
            gld_lds16(src, &s_stage[b % 3][row][0]);
        }
    };
    issue(0);
    issue(1);

    for (int b = 0; b < NPB1; ++b) {
        // wait for node b's DMA (keep b+1's in flight), then sync
        if (b < NPB1 - 1) asm volatile("s_waitcnt vmcnt(2)" ::: "memory");
        else              asm volatile("s_waitcnt vmcnt(0)" ::: "memory");
        __builtin_amdgcn_s_barrier();
        if (b + 2 < NPB1) issue(b + 2);

        // compute node b: A row = neighbor lrow, k-chunk per (ks, lk)
        const char* rowbase = (const char*)&s_stage[b % 3][lrow][0];
        f32x4 acc0 = {0.f, 0.f, 0.f, 0.f}, acc1 = {0.f, 0.f, 0.f, 0.f};
        #pragma unroll
        for (int ks = 0; ks < 8; ++ks) {
            unsigned off = ((unsigned)(ks * 128 + lk * 32)) ^ ((unsigned)lrow << 6);
            f32x4 u0 = *(const f32x4*)(rowbase + off);
            f32x4 u1 = *(const f32x4*)(rowbase + off + 16);
            bf16x8 a = pack2(u0, u1);
            acc0 = __builtin_amdgcn_mfma_f32_16x16x32_bf16(a, bF[0][ks], acc0, 0, 0, 0);
            acc1 = __builtin_amdgcn_mfma_f32_16x16x32_bf16(a, bF[1][ks], acc1, 0, 0, 0);
        }

        // epilogue: +Qb, leaky, weighted mean over rows t = lk*4 + r
        float w0 = s_wt[b * T_NB + lk * 4 + 0];
        float w1 = s_wt[b * T_NB + lk * 4 + 1];
        float w2 = s_wt[b * T_NB + lk * 4 + 2];
        float w3 = s_wt[b * T_NB + lk * 4 + 3];
        float winv = s_winv[b];
        #pragma unroll
        for (int tt = 0; tt < 2; ++tt) {
            f32x4 acc = tt ? acc1 : acc0;
            float p = 0.f, v;
            v = acc[0] + qb[tt]; v = (v > 0.f) ? v : v * NEG_SLOPE; p += w0 * v;
            v = acc[1] + qb[tt]; v = (v > 0.f) ? v : v * NEG_SLOPE; p += w1 * v;
            v = acc[2] + qb[tt]; v = (v > 0.f) ? v : v * NEG_SLOPE; p += w2 * v;
            v = acc[3] + qb[tt]; v = (v > 0.f) ? v : v * NEG_SLOPE; p += w3 * v;
            p += __shfl_xor(p, 16);
            p += __shfl_xor(p, 32);
            if (lane < 16) s_agg[b][(wid * 2 + tt) * 16 + lane] = p * winv;
        }
        // next iteration's barrier separates this batch's readers from the
        // DMA that will overwrite buf (b+3)%3 == b%3.
    }
    __syncthreads();

    // bulk coalesced agg store (16 nodes x 256 f32 = 16 KB)
    {
        const f32x4* src = (const f32x4*)&s_agg[0][0];
        f32x4* dst = (f32x4*)(agg + (long)n0 * H_DIM);
        #pragma unroll
        for (int i = tid; i < NPB1 * H_DIM / 4; i += BLK1) {
            int n = n0 + (i >> 6);
            if (n < N) dst[i] = src[i];
        }
    }
}

// ================= Kernel 2 =================
constexpr int NPB2 = 16;

__device__ __forceinline__ unsigned swz(int row, int colbyte) {
    return (unsigned)(row * 1024 + colbyte) ^ ((unsigned)(row & 7) << 4);
}

__global__ __launch_bounds__(256, 4)
void pinsage_k2(const float* __restrict__ h,
                const int*   __restrict__ nodeset,
                const float* __restrict__ agg,
                const ushort* __restrict__ Wt,
                const float* __restrict__ Wb,
                float* __restrict__ out, int N)
{
    __shared__ ushort s_cat[NPB2 * K2C];
    __shared__ float  s_part[4][NPB2];
    __shared__ float  s_ninv[NPB2];

    const int tid  = threadIdx.x;
    const int lane = tid & 63;
    const int wid  = tid >> 6;
    const int lrow = lane & 15;
    const int lk   = lane >> 4;
    const int n0   = blockIdx.x * NPB2;

    {   // stage [h_nodeset | agg] -> s_cat (bf16, swizzled)
        int r = tid >> 4, j = tid & 15;
        int n  = n0 + r;
        int nc = (n < N) ? n : N - 1;
        int idx = nodeset[nc];
        const f32x4* s1 = (const f32x4*)(h + (long)idx * D_DIM + j * 16);
        f32x4 a0 = s1[0], a1 = s1[1], a2_ = s1[2], a3 = s1[3];
        const f32x4* s2 = (const f32x4*)(agg + (long)nc * H_DIM + j * 16);
        f32x4 b0 = s2[0], b1 = s2[1], b2 = s2[2], b3 = s2[3];
        *(bf16x8*)((char*)s_cat + swz(r, j * 32))            = pack2(a0, a1);
        *(bf16x8*)((char*)s_cat + swz(r, j * 32 + 16))       = pack2(a2_, a3);
        *(bf16x8*)((char*)s_cat + swz(r, 512 + j * 32))      = pack2(b0, b1);
        *(bf16x8*)((char*)s_cat + swz(r, 512 + j * 32 + 16)) = pack2(b2, b3);
    }
    __syncthreads();

    bf16x8 a2[16];
    #pragma unroll
    for (int ks = 0; ks < 16; ++ks)
        a2[ks] = *(const bf16x8*)((char*)s_cat + swz(lrow, ks * 64 + lk * 16));

    float vout[4][4];
    float sq[4] = {0.f, 0.f, 0.f, 0.f};
    #pragma unroll
    for (int ot = 0; ot < 4; ++ot) {
        int ot_g = wid * 4 + ot;                 // output col tile 0..15
        int ocol = ot_g * 16 + lrow;
        f32x4 acc = {0.f, 0.f, 0.f, 0.f};
        #pragma unroll
        for (int ks = 0; ks < 16; ++ks) {
            // Wt[(ot_g)][ks*4+lk][lrow][8] -> 1KB contiguous per instruction
            bf16x8 bF = *(const bf16x8*)(Wt + ((ot_g * 64 + ks * 4 + lk) * 128 + lrow * 8));
            acc = __builtin_amdgcn_mfma_f32_16x16x32_bf16(a2[ks], bF, acc, 0, 0, 0);
        }
        float wb = Wb[ocol];
        #pragma unroll
        for (int r = 0; r < 4; ++r) {
            float v = acc[r] + wb;
            v = (v > 0.f) ? v : v * NEG_SLOPE;
            vout[ot][r] = v;
            sq[r] += v * v;
        }
    }
    #pragma unroll
    for (int r = 0; r < 4; ++r) {
        sq[r] += __shfl_xor(sq[r], 1);
        sq[r] += __shfl_xor(sq[r], 2);
        sq[r] += __shfl_xor(sq[r], 4);
        sq[r] += __shfl_xor(sq[r], 8);
    }
    if (lrow == 0) {
        #pragma unroll
        for (int r = 0; r < 4; ++r) s_part[wid][lk * 4 + r] = sq[r];
    }
    __syncthreads();
    if (tid < NPB2) {
        float s = s_part[0][tid] + s_part[1][tid] + s_part[2][tid] + s_part[3][tid];
        s_ninv[tid] = (s == 0.f) ? 1.f : 1.f / sqrtf(s);
    }
    __syncthreads();

    #pragma unroll
    for (int r = 0; r < 4; ++r) {
        int node = lk * 4 + r;
        int n = n0 + node;
        if (n < N) {
            float inv = s_ninv[node];
            #pragma unroll
            for (int ot = 0; ot < 4; ++ot)
                out[(long)n * O_DIM + (wid * 4 + ot) * 16 + lrow] = vout[ot][r] * inv;
        }
    }
}

// ================= Fallback (no workspace): R2 monolithic, f32 weights =================
__global__ __launch_bounds__(256, 2)
void pinsage_mono(const float* __restrict__ h,
                  const int*   __restrict__ nodeset,
                  const int*   __restrict__ nb_nodes,
                  const float* __restrict__ nb_w,
                  const float* __restrict__ Qw,
                  const float* __restrict__ Qb,
                  const float* __restrict__ Ww,
                  const float* __restrict__ Wb,
                  float* __restrict__ out, int N)
{
    __shared__ ushort s_cat[16 * K2C];
    __shared__ float  s_part[4][16];
    __shared__ float  s_ninv[16];

    const int tid  = threadIdx.x;
    const int lane = tid & 63;
    const int wid  = tid >> 6;
    const int lrow = lane & 15;
    const int lk   = lane >> 4;
    const int n0   = blockIdx.x * 16;

    {
        int r = tid >> 4, j = tid & 15;
        int n = n0 + r;
        int idx = (n < N) ? nodeset[n] : 0;
        const float* src = h + (long)idx * D_DIM + j * 16;
        f32x4 v0 = *(const f32x4*)(src + 0);
        f32x4 v1 = *(const f32x4*)(src + 4);
        f32x4 v2 = *(const f32x4*)(src + 8);
        f32x4 v3 = *(const f32x4*)(src + 12);
        *(bf16x8*)((char*)s_cat + swz(r, j * 32))      = pack2(v0, v1);
        *(bf16x8*)((char*)s_cat + swz(r, j * 32 + 16)) = pack2(v2, v3);
    }

    int   aidx[4];
    float wn[4][4];
    #pragma unroll
    for (int g = 0; g < 4; ++g) {
        int n  = n0 + wid * 4 + g;
        int nc = (n < N) ? n : 0;
        aidx[g] = nb_nodes[nc * T_NB + lrow];
        f32x4 w4 = *(const f32x4*)(nb_w + nc * T_NB + lk * 4);
        float wsum = w4.x + w4.y + w4.z + w4.w;
        wsum += __shfl_xor(wsum, 16);
        wsum += __shfl_xor(wsum, 32);
        float inv = (wsum == 0.f) ? 1.f : 1.f / wsum;
        if (n >= N) inv = 0.f;
        wn[g][0] = w4.x * inv; wn[g][1] = w4.y * inv;
        wn[g][2] = w4.z * inv; wn[g][3] = w4.w * inv;
    }

    bf16x8 aF[4][8];
    #pragma unroll
    for (int g = 0; g < 4; ++g) {
        const float* base = h + (long)aidx[g] * D_DIM + lk * 8;
        #pragma unroll
        for (int ks = 0; ks < 8; ++ks) {
            f32x4 t0 = *(const f32x4*)(base + ks * 32 + 0);
            f32x4 t1 = *(const f32x4*)(base + ks * 32 + 4);
            aF[g][ks] = pack2(t0, t1);
        }
    }

    for (int nt = 0; nt < 16; ++nt) {
        bf16x8 bF[8];
        const float* bb = Qw + (nt * 16 + lrow) * D_DIM + lk * 8;
        #pragma unroll
        for (int ks = 0; ks < 8; ++ks) {
            f32x4 t0 = *(const f32x4*)(bb + ks * 32 + 0);
            f32x4 t1 = *(const f32x4*)(bb + ks * 32 + 4);
            bF[ks] = pack2(t0, t1);
        }
        f32x4 acc[4];
        #pragma unroll
        for (int g = 0; g < 4; ++g) acc[g] = (f32x4){0.f, 0.f, 0.f, 0.f};
        #pragma unroll
        for (int g = 0; g < 4; ++g)
            #pragma unroll
            for (int ks = 0; ks < 8; ++ks)
                acc[g] = __builtin_amdgcn_mfma_f32_16x16x32_bf16(aF[g][ks], bF[ks], acc[g], 0, 0, 0);

        float qb = Qb[nt * 16 + lrow];
        #pragma unroll
        for (int g = 0; g < 4; ++g) {
            float p = 0.f;
            #pragma unroll
            for (int r = 0; r < 4; ++r) {
                float v = acc[g][r] + qb;
                v = (v > 0.f) ? v : v * NEG_SLOPE;
                p += wn[g][r] * v;
            }
            p += __shfl_xor(p, 16);
            p += __shfl_xor(p, 32);
            if (lane < 16) {
                int node = wid * 4 + g;
                *(ushort*)((char*)s_cat + swz(node, (D_DIM + nt * 16 + lane) * 2)) =
                    (ushort)f2bf(p);
            }
        }
    }
    __syncthreads();

    bf16x8 a2[16];
    #pragma unroll
    for (int ks = 0; ks < 16; ++ks)
        a2[ks] = *(const bf16x8*)((char*)s_cat + swz(lrow, ks * 64 + lk * 16));

    float vout[4][4];
    float sq[4] = {0.f, 0.f, 0.f, 0.f};
    #pragma unroll
    for (int ot = 0; ot < 4; ++ot) {
        int ocol = wid * 64 + ot * 16 + lrow;
        f32x4 acc = {0.f, 0.f, 0.f, 0.f};
        const float* bb = Ww + ocol * K2C + lk * 8;
        #pragma unroll
        for (int ks = 0; ks < 16; ++ks) {
            f32x4 t0 = *(const f32x4*)(bb + ks * 32 + 0);
            f32x4 t1 = *(const f32x4*)(bb + ks * 32 + 4);
            bf16x8 bF = pack2(t0, t1);
            acc = __builtin_amdgcn_mfma_f32_16x16x32_bf16(a2[ks], bF, acc, 0, 0, 0);
        }
        float wb = Wb[ocol];
        #pragma unroll
        for (int r = 0; r < 4; ++r) {
            float v = acc[r] + wb;
            v = (v > 0.f) ? v : v * NEG_SLOPE;
            vout[ot][r] = v;
            sq[r] += v * v;
        }
    }
    #pragma unroll
    for (int r = 0; r < 4; ++r) {
        sq[r] += __shfl_xor(sq[r], 1);
        sq[r] += __shfl_xor(sq[r], 2);
        sq[r] += __shfl_xor(sq[r], 4);
        sq[r] += __shfl_xor(sq[r], 8);
    }
    if (lrow == 0) {
        #pragma unroll
        for (int r = 0; r < 4; ++r) s_part[wid][lk * 4 + r] = sq[r];
    }
    __syncthreads();
    if (tid < 16) {
        float s = s_part[0][tid] + s_part[1][tid] + s_part[2][tid] + s_part[3][tid];
        s_ninv[tid] = (s == 0.f) ? 1.f : 1.f / sqrtf(s);
    }
    __syncthreads();

    #pragma unroll
    for (int r = 0; r < 4; ++r) {
        int node = lk * 4 + r;
        int n = n0 + node;
        if (n < N) {
            float inv = s_ninv[node];
            #pragma unroll
            for (int ot = 0; ot < 4; ++ot)
                out[(long)n * O_DIM + wid * 64 + ot * 16 + lrow] = vout[ot][r] * inv;
        }
    }
}

extern "C" void kernel_launch(void* const* d_in, const int* in_sizes, int n_in,
                              void* d_out, int out_size, void* d_ws, size_t ws_size,
                              hipStream_t stream)
{
    const float* h        = (const float*)d_in[0];
    const int*   nodeset  = (const int*)  d_in[1];
    const int*   nb_nodes = (const int*)  d_in[2];
    const float* nb_w     = (const float*)d_in[3];
    const float* Qw       = (const float*)d_in[4];
    const float* Qb       = (const float*)d_in[5];
    const float* Ww       = (const float*)d_in[6];
    const float* Wb       = (const float*)d_in[7];
    float*       out      = (float*)d_out;

    int N = in_sizes[1];

    constexpr size_t QBYTES = (size_t)H_DIM * D_DIM * sizeof(ushort);   // 128 KB
    constexpr size_t WBYTES = (size_t)O_DIM * K2C * sizeof(ushort);     // 256 KB
    const size_t AGG_BYTES  = (size_t)N * H_DIM * sizeof(float);
    const size_t NEED       = QBYTES + WBYTES + AGG_BYTES;

    if (d_ws && ws_size >= NEED) {
        ushort* Qbf = (ushort*)d_ws;
        ushort* Wt  = (ushort*)((char*)d_ws + QBYTES);
        float*  agg = (float*)((char*)d_ws + QBYTES + WBYTES);
        cvt_weights<<<(O_DIM * K2C + 255) / 256, 256, 0, stream>>>(Qw, Ww, Qbf, Wt);
        pinsage_k1<<<(N + NPB1 - 1) / NPB1, BLK1, 0, stream>>>(
            h, nb_nodes, nb_w, Qbf, Qb, agg, N);
        pinsage_k2<<<(N + NPB2 - 1) / NPB2, 256, 0, stream>>>(
            h, nodeset, agg, Wt, Wb, out, N);
    } else {
        pinsage_mono<<<(N + 15) / 16, 256, 0, stream>>>(
            h, nodeset, nb_nodes, nb_w, Qw, Qb, Ww, Wb, out, N);
    }
}

// Round 5
// 175.114 us; speedup vs baseline: 11.0593x; 1.0585x over previous
//
#include <hip/hip_runtime.h>
#include <hip/hip_bf16.h>
#include <math.h>

// PinSageConv R5: fully fused single kernel.
// Per block: 16 nodes. Neighbor rows DMA'd global->LDS (f32, source-swizzled),
// 3-buffer / 2-ahead pipeline, uniform in-loop s_waitcnt vmcnt(2) (never 0),
// raw s_barrier. Stage-A MFMA with Q register-resident (8 waves x 2 col-tiles).
// agg written bf16 directly into swizzled s_cat (no global round-trip).
// h[nodeset] rows ride the same DMA pipeline as batch 16. Stage B = 16x512 @ W^T
// MFMA from s_cat + leaky + L2-normalize, W in chunk-transposed coalesced layout.

typedef __attribute__((ext_vector_type(8))) short bf16x8;
typedef __attribute__((ext_vector_type(4))) float f32x4;

constexpr float NEG_SLOPE = 0.01f;
constexpr int T_NB  = 16;
constexpr int D_DIM = 256;
constexpr int H_DIM = 256;
constexpr int O_DIM = 256;
constexpr int K2C   = 512;

__device__ __forceinline__ short f2bf(float x) {
    __hip_bfloat16 b = __float2bfloat16(x);
    return *reinterpret_cast<short*>(&b);
}
__device__ __forceinline__ bf16x8 pack2(f32x4 a, f32x4 b) {
    bf16x8 o;
    o[0] = f2bf(a.x); o[1] = f2bf(a.y); o[2] = f2bf(a.z); o[3] = f2bf(a.w);
    o[4] = f2bf(b.x); o[5] = f2bf(b.y); o[6] = f2bf(b.z); o[7] = f2bf(b.w);
    return o;
}

#define AS_GLOBAL __attribute__((address_space(1)))
#define AS_SHARED __attribute__((address_space(3)))
__device__ __forceinline__ void gld_lds16(const void* g, void* l) {
    __builtin_amdgcn_global_load_lds((const AS_GLOBAL unsigned int*)g,
                                     (AS_SHARED unsigned int*)l, 16, 0, 0);
}

// Qbf plain [256][256]; Wt chunk-transposed: Wt[(o>>4)*64 + (k>>3)][ (o&15)*8 + (k&7) ]
__global__ void cvt_weights(const float* __restrict__ Qw,
                            const float* __restrict__ Ww,
                            ushort* __restrict__ qdst,
                            ushort* __restrict__ wdst) {
    int i = blockIdx.x * blockDim.x + threadIdx.x;
    if (i < H_DIM * D_DIM) qdst[i] = (ushort)f2bf(Qw[i]);
    if (i < O_DIM * K2C) {
        int o = i >> 9, k = i & 511;
        wdst[((o >> 4) * 64 + (k >> 3)) * 128 + (o & 15) * 8 + (k & 7)] =
            (ushort)f2bf(Ww[i]);
    }
}

// ================= fused kernel =================
constexpr int BLK1 = 512;   // 8 waves
constexpr int NPB1 = 16;    // nodes per block (1 node per pipeline batch)

// swizzled byte offset into s_cat rows of 1024 B
__device__ __forceinline__ unsigned swz(int row, int colbyte) {
    return (unsigned)(row * 1024 + colbyte) ^ ((unsigned)(row & 7) << 4);
}

__global__ __launch_bounds__(BLK1, 4)
void pinsage_fused(const float* __restrict__ h,
                   const int*   __restrict__ nodeset,
                   const int*   __restrict__ nb_nodes,
                   const float* __restrict__ nb_w,
                   const ushort* __restrict__ Qbf,
                   const float* __restrict__ Qb,
                   const ushort* __restrict__ Wt,
                   const float* __restrict__ Wb,
                   float* __restrict__ out,
                   int N)
{
    __shared__ float  s_stage[3][T_NB][D_DIM];  // 48 KB, source-swizzled f32
    __shared__ ushort s_cat[NPB1 * K2C];        // 16 KB, swizzled bf16 [16][512]
    __shared__ int    s_idx[NPB1 * T_NB];
    __shared__ float  s_wt[NPB1 * T_NB];
    __shared__ float  s_winv[NPB1];
    __shared__ int    s_nidx[NPB1];
    __shared__ float  s_part[8][NPB1];
    __shared__ float  s_ninv[NPB1];

    const int tid  = threadIdx.x;
    const int lane = tid & 63;
    const int wid  = tid >> 6;      // 0..7
    const int lrow = lane & 15;
    const int lk   = lane >> 4;
    const int n0   = blockIdx.x * NPB1;

    // ---- prologue: all non-DMA global loads happen before the loop ----
    if (tid < NPB1 * T_NB) {
        int n  = n0 + (tid >> 4);
        int nc = (n < N) ? n : N - 1;
        s_idx[tid] = nb_nodes[nc * T_NB + (tid & 15)];
        s_wt[tid]  = (n < N) ? nb_w[nc * T_NB + (tid & 15)] : 0.f;
    }
    if (tid >= 448 && tid < 448 + NPB1) {   // different wave than s_idx writers
        int r = tid - 448;
        int n = n0 + r;
        s_nidx[r] = nodeset[(n < N) ? n : N - 1];
    }
    __syncthreads();
    if (tid < NPB1) {
        float s = 0.f;
        #pragma unroll
        for (int t = 0; t < T_NB; ++t) s += s_wt[tid * T_NB + t];
        s_winv[tid] = (s == 0.f) ? 1.f : 1.f / s;
    }
    // Q fragments: wave owns col-tiles nt = wid*2 + tt
    bf16x8 bF[2][8];
    float  qb[2];
    #pragma unroll
    for (int tt = 0; tt < 2; ++tt) {
        int nt = wid * 2 + tt;
        const ushort* bb = Qbf + (nt * 16 + lrow) * D_DIM + lk * 8;
        #pragma unroll
        for (int ks = 0; ks < 8; ++ks)
            bF[tt][ks] = *(const bf16x8*)(bb + ks * 32);
        qb[tt] = Qb[nt * 16 + lrow];
    }
    __syncthreads();   // drains prologue vmem -> in-loop vmcnt counts DMA only

    // ---- DMA: wave stages rows {2*wid, 2*wid+1}; source chunk pre-swizzled
    // so linear LDS holds LDS[r][c] = G[r][c ^ 4r] (16B chunks).
    auto issue = [&](int b) {
        #pragma unroll
        for (int rr = 0; rr < 2; ++rr) {
            int row = wid * 2 + rr;
            int idx = s_idx[b * T_NB + row];
            const float* src = h + (long)idx * D_DIM + ((lane ^ (row << 2)) << 2);
            gld_lds16(src, &s_stage[b % 3][row][0]);
        }
    };
    auto issue_ns = [&]() {   // nodeset rows -> buffer 16%3 == 1
        #pragma unroll
        for (int rr = 0; rr < 2; ++rr) {
            int row = wid * 2 + rr;
            int idx = s_nidx[row];
            const float* src = h + (long)idx * D_DIM + ((lane ^ (row << 2)) << 2);
            gld_lds16(src, &s_stage[1][row][0]);
        }
    };
    issue(0);
    issue(1);

    for (int b = 0; b < NPB1; ++b) {
        // wait for node b's 2 DMA loads; keep later batches in flight
        asm volatile("s_waitcnt vmcnt(2)" ::: "memory");
        __builtin_amdgcn_s_barrier();
        if (b + 2 < NPB1)       issue(b + 2);
        else if (b + 2 == NPB1) issue_ns();

        // compute node b: A row = neighbor lrow
        const char* rowbase = (const char*)&s_stage[b % 3][lrow][0];
        f32x4 acc0 = {0.f, 0.f, 0.f, 0.f}, acc1 = {0.f, 0.f, 0.f, 0.f};
        #pragma unroll
        for (int ks = 0; ks < 8; ++ks) {
            unsigned off = ((unsigned)(ks * 128 + lk * 32)) ^ ((unsigned)lrow << 6);
            f32x4 u0 = *(const f32x4*)(rowbase + off);
            f32x4 u1 = *(const f32x4*)(rowbase + off + 16);
            bf16x8 a = pack2(u0, u1);
            acc0 = __builtin_amdgcn_mfma_f32_16x16x32_bf16(a, bF[0][ks], acc0, 0, 0, 0);
            acc1 = __builtin_amdgcn_mfma_f32_16x16x32_bf16(a, bF[1][ks], acc1, 0, 0, 0);
        }

        // epilogue: +Qb, leaky, weighted mean over rows t = lk*4 + r -> s_cat bf16
        float w0 = s_wt[b * T_NB + lk * 4 + 0];
        float w1 = s_wt[b * T_NB + lk * 4 + 1];
        float w2 = s_wt[b * T_NB + lk * 4 + 2];
        float w3 = s_wt[b * T_NB + lk * 4 + 3];
        float winv = s_winv[b];
        #pragma unroll
        for (int tt = 0; tt < 2; ++tt) {
            f32x4 acc = tt ? acc1 : acc0;
            float p = 0.f, v;
            v = acc[0] + qb[tt]; v = (v > 0.f) ? v : v * NEG_SLOPE; p += w0 * v;
            v = acc[1] + qb[tt]; v = (v > 0.f) ? v : v * NEG_SLOPE; p += w1 * v;
            v = acc[2] + qb[tt]; v = (v > 0.f) ? v : v * NEG_SLOPE; p += w2 * v;
            v = acc[3] + qb[tt]; v = (v > 0.f) ? v : v * NEG_SLOPE; p += w3 * v;
            p += __shfl_xor(p, 16);
            p += __shfl_xor(p, 32);
            if (lane < 16)
                *(ushort*)((char*)s_cat + swz(b, (D_DIM + (wid * 2 + tt) * 16 + lane) * 2)) =
                    (ushort)f2bf(p * winv);
        }
    }

    // drain nodeset DMA, convert f32 stage -> s_cat left half (bf16, swizzled)
    asm volatile("s_waitcnt vmcnt(0)" ::: "memory");
    __builtin_amdgcn_s_barrier();
    {
        int r = tid >> 5;          // node row 0..15
        int j = tid & 31;          // 8-float group 0..31
        const char* sb = (const char*)&s_stage[1][r][0];
        unsigned off = ((unsigned)(j * 32)) ^ ((unsigned)r << 6);
        f32x4 u0 = *(const f32x4*)(sb + off);
        f32x4 u1 = *(const f32x4*)(sb + off + 16);
        *(bf16x8*)((char*)s_cat + swz(r, j * 16)) = pack2(u0, u1);
    }
    __syncthreads();

    // ---- stage B: (16 x 512) @ W^T; wave owns 2 output col-tiles ----
    bf16x8 a2[16];
    #pragma unroll
    for (int ks = 0; ks < 16; ++ks)
        a2[ks] = *(const bf16x8*)((char*)s_cat + swz(lrow, ks * 64 + lk * 16));

    float vout[2][4];
    float sq[4] = {0.f, 0.f, 0.f, 0.f};
    #pragma unroll
    for (int tt = 0; tt < 2; ++tt) {
        int ot_g = wid * 2 + tt;                 // output col tile 0..15
        int ocol = ot_g * 16 + lrow;
        f32x4 acc = {0.f, 0.f, 0.f, 0.f};
        #pragma unroll
        for (int ks = 0; ks < 16; ++ks) {
            // Wt: 1KB contiguous per (tile, ks*4+lk)
            bf16x8 wF = *(const bf16x8*)(Wt + ((ot_g * 64 + ks * 4 + lk) * 128 + lrow * 8));
            acc = __builtin_amdgcn_mfma_f32_16x16x32_bf16(a2[ks], wF, acc, 0, 0, 0);
        }
        float wb = Wb[ocol];
        #pragma unroll
        for (int r = 0; r < 4; ++r) {
            float v = acc[r] + wb;               // row node = lk*4+r, col = ocol
            v = (v > 0.f) ? v : v * NEG_SLOPE;
            vout[tt][r] = v;
            sq[r] += v * v;
        }
    }
    #pragma unroll
    for (int r = 0; r < 4; ++r) {
        sq[r] += __shfl_xor(sq[r], 1);
        sq[r] += __shfl_xor(sq[r], 2);
        sq[r] += __shfl_xor(sq[r], 4);
        sq[r] += __shfl_xor(sq[r], 8);
    }
    if (lrow == 0) {
        #pragma unroll
        for (int r = 0; r < 4; ++r) s_part[wid][lk * 4 + r] = sq[r];
    }
    __syncthreads();
    if (tid < NPB1) {
        float s = 0.f;
        #pragma unroll
        for (int w = 0; w < 8; ++w) s += s_part[w][tid];
        s_ninv[tid] = (s == 0.f) ? 1.f : 1.f / sqrtf(s);
    }
    __syncthreads();

    #pragma unroll
    for (int r = 0; r < 4; ++r) {
        int node = lk * 4 + r;
        int n = n0 + node;
        if (n < N) {
            float inv = s_ninv[node];
            #pragma unroll
            for (int tt = 0; tt < 2; ++tt)
                out[(long)n * O_DIM + (wid * 2 + tt) * 16 + lrow] = vout[tt][r] * inv;
        }
    }
}

// ================= Fallback (no workspace): monolithic f32-weight =================
__global__ __launch_bounds__(256, 2)
void pinsage_mono(const float* __restrict__ h,
                  const int*   __restrict__ nodeset,
                  const int*   __restrict__ nb_nodes,
                  const float* __restrict__ nb_w,
                  const float* __restrict__ Qw,
                  const float* __restrict__ Qb,
                  const float* __restrict__ Ww,
                  const float* __restrict__ Wb,
                  float* __restrict__ out, int N)
{
    __shared__ ushort s_cat[16 * K2C];
    __shared__ float  s_part[4][16];
    __shared__ float  s_ninv[16];

    const int tid  = threadIdx.x;
    const int lane = tid & 63;
    const int wid  = tid >> 6;
    const int lrow = lane & 15;
    const int lk   = lane >> 4;
    const int n0   = blockIdx.x * 16;

    {
        int r = tid >> 4, j = tid & 15;
        int n = n0 + r;
        int idx = (n < N) ? nodeset[n] : 0;
        const float* src = h + (long)idx * D_DIM + j * 16;
        f32x4 v0 = *(const f32x4*)(src + 0);
        f32x4 v1 = *(const f32x4*)(src + 4);
        f32x4 v2 = *(const f32x4*)(src + 8);
        f32x4 v3 = *(const f32x4*)(src + 12);
        *(bf16x8*)((char*)s_cat + swz(r, j * 32))      = pack2(v0, v1);
        *(bf16x8*)((char*)s_cat + swz(r, j * 32 + 16)) = pack2(v2, v3);
    }

    int   aidx[4];
    float wn[4][4];
    #pragma unroll
    for (int g = 0; g < 4; ++g) {
        int n  = n0 + wid * 4 + g;
        int nc = (n < N) ? n : 0;
        aidx[g] = nb_nodes[nc * T_NB + lrow];
        f32x4 w4 = *(const f32x4*)(nb_w + nc * T_NB + lk * 4);
        float wsum = w4.x + w4.y + w4.z + w4.w;
        wsum += __shfl_xor(wsum, 16);
        wsum += __shfl_xor(wsum, 32);
        float inv = (wsum == 0.f) ? 1.f : 1.f / wsum;
        if (n >= N) inv = 0.f;
        wn[g][0] = w4.x * inv; wn[g][1] = w4.y * inv;
        wn[g][2] = w4.z * inv; wn[g][3] = w4.w * inv;
    }

    bf16x8 aF[4][8];
    #pragma unroll
    for (int g = 0; g < 4; ++g) {
        const float* base = h + (long)aidx[g] * D_DIM + lk * 8;
        #pragma unroll
        for (int ks = 0; ks < 8; ++ks) {
            f32x4 t0 = *(const f32x4*)(base + ks * 32 + 0);
            f32x4 t1 = *(const f32x4*)(base + ks * 32 + 4);
            aF[g][ks] = pack2(t0, t1);
        }
    }

    for (int nt = 0; nt < 16; ++nt) {
        bf16x8 bF[8];
        const float* bb = Qw + (nt * 16 + lrow) * D_DIM + lk * 8;
        #pragma unroll
        for (int ks = 0; ks < 8; ++ks) {
            f32x4 t0 = *(const f32x4*)(bb + ks * 32 + 0);
            f32x4 t1 = *(const f32x4*)(bb + ks * 32 + 4);
            bF[ks] = pack2(t0, t1);
        }
        f32x4 acc[4];
        #pragma unroll
        for (int g = 0; g < 4; ++g) acc[g] = (f32x4){0.f, 0.f, 0.f, 0.f};
        #pragma unroll
        for (int g = 0; g < 4; ++g)
            #pragma unroll
            for (int ks = 0; ks < 8; ++ks)
                acc[g] = __builtin_amdgcn_mfma_f32_16x16x32_bf16(aF[g][ks], bF[ks], acc[g], 0, 0, 0);

        float qb = Qb[nt * 16 + lrow];
        #pragma unroll
        for (int g = 0; g < 4; ++g) {
            float p = 0.f;
            #pragma unroll
            for (int r = 0; r < 4; ++r) {
                float v = acc[g][r] + qb;
                v = (v > 0.f) ? v : v * NEG_SLOPE;
                p += wn[g][r] * v;
            }
            p += __shfl_xor(p, 16);
            p += __shfl_xor(p, 32);
            if (lane < 16) {
                int node = wid * 4 + g;
                *(ushort*)((char*)s_cat + swz(node, (D_DIM + nt * 16 + lane) * 2)) =
                    (ushort)f2bf(p);
            }
        }
    }
    __syncthreads();

    bf16x8 a2[16];
    #pragma unroll
    for (int ks = 0; ks < 16; ++ks)
        a2[ks] = *(const bf16x8*)((char*)s_cat + swz(lrow, ks * 64 + lk * 16));

    float vout[4][4];
    float sq[4] = {0.f, 0.f, 0.f, 0.f};
    #pragma unroll
    for (int ot = 0; ot < 4; ++ot) {
        int ocol = wid * 64 + ot * 16 + lrow;
        f32x4 acc = {0.f, 0.f, 0.f, 0.f};
        const float* bb = Ww + ocol * K2C + lk * 8;
        #pragma unroll
        for (int ks = 0; ks < 16; ++ks) {
            f32x4 t0 = *(const f32x4*)(bb + ks * 32 + 0);
            f32x4 t1 = *(const f32x4*)(bb + ks * 32 + 4);
            bf16x8 bFk = pack2(t0, t1);
            acc = __builtin_amdgcn_mfma_f32_16x16x32_bf16(a2[ks], bFk, acc, 0, 0, 0);
        }
        float wb = Wb[ocol];
        #pragma unroll
        for (int r = 0; r < 4; ++r) {
            float v = acc[r] + wb;
            v = (v > 0.f) ? v : v * NEG_SLOPE;
            vout[ot][r] = v;
            sq[r] += v * v;
        }
    }
    #pragma unroll
    for (int r = 0; r < 4; ++r) {
        sq[r] += __shfl_xor(sq[r], 1);
        sq[r] += __shfl_xor(sq[r], 2);
        sq[r] += __shfl_xor(sq[r], 4);
        sq[r] += __shfl_xor(sq[r], 8);
    }
    if (lrow == 0) {
        #pragma unroll
        for (int r = 0; r < 4; ++r) s_part[wid][lk * 4 + r] = sq[r];
    }
    __syncthreads();
    if (tid < 16) {
        float s = s_part[0][tid] + s_part[1][tid] + s_part[2][tid] + s_part[3][tid];
        s_ninv[tid] = (s == 0.f) ? 1.f : 1.f / sqrtf(s);
    }
    __syncthreads();

    #pragma unroll
    for (int r = 0; r < 4; ++r) {
        int node = lk * 4 + r;
        int n = n0 + node;
        if (n < N) {
            float inv = s_ninv[node];
            #pragma unroll
            for (int ot = 0; ot < 4; ++ot)
                out[(long)n * O_DIM + wid * 64 + ot * 16 + lrow] = vout[ot][r] * inv;
        }
    }
}

extern "C" void kernel_launch(void* const* d_in, const int* in_sizes, int n_in,
                              void* d_out, int out_size, void* d_ws, size_t ws_size,
                              hipStream_t stream)
{
    const float* h        = (const float*)d_in[0];
    const int*   nodeset  = (const int*)  d_in[1];
    const int*   nb_nodes = (const int*)  d_in[2];
    const float* nb_w     = (const float*)d_in[3];
    const float* Qw       = (const float*)d_in[4];
    const float* Qb       = (const float*)d_in[5];
    const float* Ww       = (const float*)d_in[6];
    const float* Wb       = (const float*)d_in[7];
    float*       out      = (float*)d_out;

    int N = in_sizes[1];

    constexpr size_t QBYTES = (size_t)H_DIM * D_DIM * sizeof(ushort);   // 128 KB
    constexpr size_t WBYTES = (size_t)O_DIM * K2C * sizeof(ushort);     // 256 KB

    if (d_ws && ws_size >= QBYTES + WBYTES) {
        ushort* Qbf = (ushort*)d_ws;
        ushort* Wt  = (ushort*)((char*)d_ws + QBYTES);
        cvt_weights<<<(O_DIM * K2C + 255) / 256, 256, 0, stream>>>(Qw, Ww, Qbf, Wt);
        pinsage_fused<<<(N + NPB1 - 1) / NPB1, BLK1, 0, stream>>>(
            h, nodeset, nb_nodes, nb_w, Qbf, Qb, Wt, Wb, out, N);
    } else {
        pinsage_mono<<<(N + 15) / 16, 256, 0, stream>>>(
            h, nodeset, nb_nodes, nb_w, Qw, Qb, Ww, Wb, out, N);
    }
}

// Round 6
// 137.664 us; speedup vs baseline: 14.0679x; 1.2720x over previous
//
#include <hip/hip_runtime.h>
#include <hip/hip_bf16.h>
#include <math.h>

// PinSageConv R6: fused, reg-staged pipeline (T14).
// Per block 16 nodes. Each batch (1 node, 16 rows x 1KB): threads load 32B f32
// to VGPRs (counted vmcnt handled by compiler), cvt->bf16, ds_write swizzled.
// 2-deep double buffer, lgkmcnt(0)+raw s_barrier (NO vmcnt drain in loop).
// Stage-A MFMA with Q register-resident (8 waves x 2 col-tiles); agg -> s_cat
// bf16; nodeset rows ride as batch 16 -> s_cat left half. Stage B from s_cat.

typedef __attribute__((ext_vector_type(8))) short bf16x8;
typedef __attribute__((ext_vector_type(4))) float f32x4;

constexpr float NEG_SLOPE = 0.01f;
constexpr int T_NB  = 16;
constexpr int D_DIM = 256;
constexpr int H_DIM = 256;
constexpr int O_DIM = 256;
constexpr int K2C   = 512;

__device__ __forceinline__ short f2bf(float x) {
    __hip_bfloat16 b = __float2bfloat16(x);
    return *reinterpret_cast<short*>(&b);
}
__device__ __forceinline__ bf16x8 pack2(f32x4 a, f32x4 b) {
    bf16x8 o;
    o[0] = f2bf(a.x); o[1] = f2bf(a.y); o[2] = f2bf(a.z); o[3] = f2bf(a.w);
    o[4] = f2bf(b.x); o[5] = f2bf(b.y); o[6] = f2bf(b.z); o[7] = f2bf(b.w);
    return o;
}

// Qbf plain [256][256]; Wt chunk-transposed: Wt[(o>>4)*64 + (k>>3)][(o&15)*8 + (k&7)]
__global__ void cvt_weights(const float* __restrict__ Qw,
                            const float* __restrict__ Ww,
                            ushort* __restrict__ qdst,
                            ushort* __restrict__ wdst) {
    int i = blockIdx.x * blockDim.x + threadIdx.x;
    if (i < H_DIM * D_DIM) qdst[i] = (ushort)f2bf(Qw[i]);
    if (i < O_DIM * K2C) {
        int o = i >> 9, k = i & 511;
        wdst[((o >> 4) * 64 + (k >> 3)) * 128 + (o & 15) * 8 + (k & 7)] =
            (ushort)f2bf(Ww[i]);
    }
}

// ================= fused kernel =================
constexpr int BLK1 = 512;   // 8 waves
constexpr int NPB1 = 16;    // nodes per block (1 node per pipeline batch)

// swizzled byte offset into s_cat rows of 1024 B
__device__ __forceinline__ unsigned swz(int row, int colbyte) {
    return (unsigned)(row * 1024 + colbyte) ^ ((unsigned)(row & 7) << 4);
}

__global__ __launch_bounds__(BLK1, 4)
void pinsage_fused(const float* __restrict__ h,
                   const int*   __restrict__ nodeset,
                   const int*   __restrict__ nb_nodes,
                   const float* __restrict__ nb_w,
                   const ushort* __restrict__ Qbf,
                   const float* __restrict__ Qb,
                   const ushort* __restrict__ Wt,
                   const float* __restrict__ Wb,
                   float* __restrict__ out,
                   int N)
{
    // bf16 stage: [2 bufs][16 rows][32 slots of 16B], slot = chunk ^ ((row&7)<<2)
    __shared__ ushort s_stage[2 * 16 * 256];    // 16 KB
    __shared__ ushort s_cat[NPB1 * K2C];        // 16 KB, swizzled bf16 [16][512]
    __shared__ int    s_idx[NPB1 * T_NB];
    __shared__ float  s_wt[NPB1 * T_NB];
    __shared__ float  s_winv[NPB1];
    __shared__ int    s_nidx[NPB1];
    __shared__ float  s_part[8][NPB1];
    __shared__ float  s_ninv[NPB1];

    const int tid  = threadIdx.x;
    const int lane = tid & 63;
    const int wid  = tid >> 6;      // 0..7
    const int lrow = lane & 15;
    const int lk   = lane >> 4;
    const int n0   = blockIdx.x * NPB1;

    // staging role: thread covers row = tid>>5 (0..15), 32B chunk ch = tid&31
    const int sRow = tid >> 5;
    const int sCh  = tid & 31;

    // ---- prologue ----
    if (tid < NPB1 * T_NB) {
        int n  = n0 + (tid >> 4);
        int nc = (n < N) ? n : N - 1;
        s_idx[tid] = nb_nodes[nc * T_NB + (tid & 15)];
        s_wt[tid]  = (n < N) ? nb_w[nc * T_NB + (tid & 15)] : 0.f;
    }
    if (tid >= 448 && tid < 448 + NPB1) {
        int r = tid - 448;
        int n = n0 + r;
        s_nidx[r] = nodeset[(n < N) ? n : N - 1];
    }
    __syncthreads();
    if (tid < NPB1) {
        float s = 0.f;
        #pragma unroll
        for (int t = 0; t < T_NB; ++t) s += s_wt[tid * T_NB + t];
        s_winv[tid] = (s == 0.f) ? 1.f : 1.f / s;
    }
    // Q fragments: wave owns col-tiles nt = wid*2 + tt
    bf16x8 bF[2][8];
    float  qb[2];
    #pragma unroll
    for (int tt = 0; tt < 2; ++tt) {
        int nt = wid * 2 + tt;
        const ushort* bb = Qbf + (nt * 16 + lrow) * D_DIM + lk * 8;
        #pragma unroll
        for (int ks = 0; ks < 8; ++ks)
            bF[tt][ks] = *(const bf16x8*)(bb + ks * 32);
        qb[tt] = Qb[nt * 16 + lrow];
    }

    // ---- staging helpers (reg-staged, compiler does counted vmcnt) ----
    auto stage_issue = [&](int b, f32x4& a, f32x4& c) {
        int idx = (b == 16) ? s_nidx[sRow] : s_idx[b * T_NB + sRow];
        const f32x4* src = (const f32x4*)(h + (long)idx * D_DIM + sCh * 8);
        a = src[0]; c = src[1];
    };
    auto stage_commit = [&](int b, f32x4 a, f32x4 c) {
        bf16x8 p = pack2(a, c);
        if (b == 16) {
            *(bf16x8*)((char*)s_cat + swz(sRow, sCh * 16)) = p;
        } else {
            int slot = sCh ^ ((sRow & 7) << 2);
            *(bf16x8*)((char*)s_stage +
                       ((b & 1) * 8192 + sRow * 512 + slot * 16)) = p;
        }
    };

    // ---- per-batch compute: A from s_stage[b&1], epilogue -> s_cat ----
    auto compute = [&](int b) {
        const char* base = (const char*)s_stage + (b & 1) * 8192 + lrow * 512;
        f32x4 acc0 = {0.f, 0.f, 0.f, 0.f}, acc1 = {0.f, 0.f, 0.f, 0.f};
        #pragma unroll
        for (int ks = 0; ks < 8; ++ks) {
            int slot = (ks * 4 + lk) ^ ((lrow & 7) << 2);
            bf16x8 a = *(const bf16x8*)(base + slot * 16);
            acc0 = __builtin_amdgcn_mfma_f32_16x16x32_bf16(a, bF[0][ks], acc0, 0, 0, 0);
            acc1 = __builtin_amdgcn_mfma_f32_16x16x32_bf16(a, bF[1][ks], acc1, 0, 0, 0);
        }
        float w0 = s_wt[b * T_NB + lk * 4 + 0];
        float w1 = s_wt[b * T_NB + lk * 4 + 1];
        float w2 = s_wt[b * T_NB + lk * 4 + 2];
        float w3 = s_wt[b * T_NB + lk * 4 + 3];
        float winv = s_winv[b];
        #pragma unroll
        for (int tt = 0; tt < 2; ++tt) {
            f32x4 acc = tt ? acc1 : acc0;
            float p = 0.f, v;
            v = acc[0] + qb[tt]; v = (v > 0.f) ? v : v * NEG_SLOPE; p += w0 * v;
            v = acc[1] + qb[tt]; v = (v > 0.f) ? v : v * NEG_SLOPE; p += w1 * v;
            v = acc[2] + qb[tt]; v = (v > 0.f) ? v : v * NEG_SLOPE; p += w2 * v;
            v = acc[3] + qb[tt]; v = (v > 0.f) ? v : v * NEG_SLOPE; p += w3 * v;
            p += __shfl_xor(p, 16);
            p += __shfl_xor(p, 32);
            if (lane < 16)
                *(ushort*)((char*)s_cat +
                           swz(b, (D_DIM + (wid * 2 + tt) * 16 + lane) * 2)) =
                    (ushort)f2bf(p * winv);
        }
    };

    // barrier with LDS visibility but NO vmcnt drain
    #define BAR() do { \
        asm volatile("s_waitcnt lgkmcnt(0)" ::: "memory"); \
        __builtin_amdgcn_s_barrier(); \
    } while (0)

    // ---- pipeline: 2-deep, named reg sets (static indexing) ----
    f32x4 uA0, uA1, uB0, uB1;
    stage_issue(0, uA0, uA1);
    stage_issue(1, uB0, uB1);
    stage_commit(0, uA0, uA1);          // waits uA only (uB stays in flight)
    BAR();

    for (int bb = 0; bb < 8; ++bb) {
        const int b = bb * 2;
        // even phase: issue b+2 early, compute b (buf0), commit b+1 (buf1) late
        stage_issue(b + 2, uA0, uA1);
        compute(b);
        stage_commit(b + 1, uB0, uB1);
        BAR();
        // odd phase: issue b+3, compute b+1 (buf1), commit b+2 late
        if (b + 3 <= 16) stage_issue(b + 3, uB0, uB1);
        compute(b + 1);
        stage_commit(b + 2, uA0, uA1);  // b==14 -> commit(16) writes s_cat
        BAR();
    }
    #undef BAR

    // ---- stage B: (16 x 512) @ W^T; wave owns 2 output col-tiles ----
    bf16x8 a2[16];
    #pragma unroll
    for (int ks = 0; ks < 16; ++ks)
        a2[ks] = *(const bf16x8*)((char*)s_cat + swz(lrow, ks * 64 + lk * 16));

    float vout[2][4];
    float sq[4] = {0.f, 0.f, 0.f, 0.f};
    #pragma unroll
    for (int tt = 0; tt < 2; ++tt) {
        int ot_g = wid * 2 + tt;
        int ocol = ot_g * 16 + lrow;
        f32x4 acc = {0.f, 0.f, 0.f, 0.f};
        #pragma unroll
        for (int ks = 0; ks < 16; ++ks) {
            bf16x8 wF = *(const bf16x8*)(Wt + ((ot_g * 64 + ks * 4 + lk) * 128 + lrow * 8));
            acc = __builtin_amdgcn_mfma_f32_16x16x32_bf16(a2[ks], wF, acc, 0, 0, 0);
        }
        float wb = Wb[ocol];
        #pragma unroll
        for (int r = 0; r < 4; ++r) {
            float v = acc[r] + wb;
            v = (v > 0.f) ? v : v * NEG_SLOPE;
            vout[tt][r] = v;
            sq[r] += v * v;
        }
    }
    #pragma unroll
    for (int r = 0; r < 4; ++r) {
        sq[r] += __shfl_xor(sq[r], 1);
        sq[r] += __shfl_xor(sq[r], 2);
        sq[r] += __shfl_xor(sq[r], 4);
        sq[r] += __shfl_xor(sq[r], 8);
    }
    if (lrow == 0) {
        #pragma unroll
        for (int r = 0; r < 4; ++r) s_part[wid][lk * 4 + r] = sq[r];
    }
    __syncthreads();
    if (tid < NPB1) {
        float s = 0.f;
        #pragma unroll
        for (int w = 0; w < 8; ++w) s += s_part[w][tid];
        s_ninv[tid] = (s == 0.f) ? 1.f : 1.f / sqrtf(s);
    }
    __syncthreads();

    #pragma unroll
    for (int r = 0; r < 4; ++r) {
        int node = lk * 4 + r;
        int n = n0 + node;
        if (n < N) {
            float inv = s_ninv[node];
            #pragma unroll
            for (int tt = 0; tt < 2; ++tt)
                out[(long)n * O_DIM + (wid * 2 + tt) * 16 + lrow] = vout[tt][r] * inv;
        }
    }
}

// ================= Fallback (no workspace): monolithic f32-weight =================
__global__ __launch_bounds__(256, 2)
void pinsage_mono(const float* __restrict__ h,
                  const int*   __restrict__ nodeset,
                  const int*   __restrict__ nb_nodes,
                  const float* __restrict__ nb_w,
                  const float* __restrict__ Qw,
                  const float* __restrict__ Qb,
                  const float* __restrict__ Ww,
                  const float* __restrict__ Wb,
                  float* __restrict__ out, int N)
{
    __shared__ ushort s_cat[16 * K2C];
    __shared__ float  s_part[4][16];
    __shared__ float  s_ninv[16];

    const int tid  = threadIdx.x;
    const int lane = tid & 63;
    const int wid  = tid >> 6;
    const int lrow = lane & 15;
    const int lk   = lane >> 4;
    const int n0   = blockIdx.x * 16;

    {
        int r = tid >> 4, j = tid & 15;
        int n = n0 + r;
        int idx = (n < N) ? nodeset[n] : 0;
        const float* src = h + (long)idx * D_DIM + j * 16;
        f32x4 v0 = *(const f32x4*)(src + 0);
        f32x4 v1 = *(const f32x4*)(src + 4);
        f32x4 v2 = *(const f32x4*)(src + 8);
        f32x4 v3 = *(const f32x4*)(src + 12);
        *(bf16x8*)((char*)s_cat + swz(r, j * 32))      = pack2(v0, v1);
        *(bf16x8*)((char*)s_cat + swz(r, j * 32 + 16)) = pack2(v2, v3);
    }

    int   aidx[4];
    float wn[4][4];
    #pragma unroll
    for (int g = 0; g < 4; ++g) {
        int n  = n0 + wid * 4 + g;
        int nc = (n < N) ? n : 0;
        aidx[g] = nb_nodes[nc * T_NB + lrow];
        f32x4 w4 = *(const f32x4*)(nb_w + nc * T_NB + lk * 4);
        float wsum = w4.x + w4.y + w4.z + w4.w;
        wsum += __shfl_xor(wsum, 16);
        wsum += __shfl_xor(wsum, 32);
        float inv = (wsum == 0.f) ? 1.f : 1.f / wsum;
        if (n >= N) inv = 0.f;
        wn[g][0] = w4.x * inv; wn[g][1] = w4.y * inv;
        wn[g][2] = w4.z * inv; wn[g][3] = w4.w * inv;
    }

    bf16x8 aF[4][8];
    #pragma unroll
    for (int g = 0; g < 4; ++g) {
        const float* base = h + (long)aidx[g] * D_DIM + lk * 8;
        #pragma unroll
        for (int ks = 0; ks < 8; ++ks) {
            f32x4 t0 = *(const f32x4*)(base + ks * 32 + 0);
            f32x4 t1 = *(const f32x4*)(base + ks * 32 + 4);
            aF[g][ks] = pack2(t0, t1);
        }
    }

    for (int nt = 0; nt < 16; ++nt) {
        bf16x8 bF[8];
        const float* bb = Qw + (nt * 16 + lrow) * D_DIM + lk * 8;
        #pragma unroll
        for (int ks = 0; ks < 8; ++ks) {
            f32x4 t0 = *(const f32x4*)(bb + ks * 32 + 0);
            f32x4 t1 = *(const f32x4*)(bb + ks * 32 + 4);
            bF[ks] = pack2(t0, t1);
        }
        f32x4 acc[4];
        #pragma unroll
        for (int g = 0; g < 4; ++g) acc[g] = (f32x4){0.f, 0.f, 0.f, 0.f};
        #pragma unroll
        for (int g = 0; g < 4; ++g)
            #pragma unroll
            for (int ks = 0; ks < 8; ++ks)
                acc[g] = __builtin_amdgcn_mfma_f32_16x16x32_bf16(aF[g][ks], bF[ks], acc[g], 0, 0, 0);

        float qb = Qb[nt * 16 + lrow];
        #pragma unroll
        for (int g = 0; g < 4; ++g) {
            float p = 0.f;
            #pragma unroll
            for (int r = 0; r < 4; ++r) {
                float v = acc[g][r] + qb;
                v = (v > 0.f) ? v : v * NEG_SLOPE;
                p += wn[g][r] * v;
            }
            p += __shfl_xor(p, 16);
            p += __shfl_xor(p, 32);
            if (lane < 16) {
                int node = wid * 4 + g;
                *(ushort*)((char*)s_cat + swz(node, (D_DIM + nt * 16 + lane) * 2)) =
                    (ushort)f2bf(p);
            }
        }
    }
    __syncthreads();

    bf16x8 a2[16];
    #pragma unroll
    for (int ks = 0; ks < 16; ++ks)
        a2[ks] = *(const bf16x8*)((char*)s_cat + swz(lrow, ks * 64 + lk * 16));

    float vout[4][4];
    float sq[4] = {0.f, 0.f, 0.f, 0.f};
    #pragma unroll
    for (int ot = 0; ot < 4; ++ot) {
        int ocol = wid * 64 + ot * 16 + lrow;
        f32x4 acc = {0.f, 0.f, 0.f, 0.f};
        const float* bb = Ww + ocol * K2C + lk * 8;
        #pragma unroll
        for (int ks = 0; ks < 16; ++ks) {
            f32x4 t0 = *(const f32x4*)(bb + ks * 32 + 0);
            f32x4 t1 = *(const f32x4*)(bb + ks * 32 + 4);
            bf16x8 bFk = pack2(t0, t1);
            acc = __builtin_amdgcn_mfma_f32_16x16x32_bf16(a2[ks], bFk, acc, 0, 0, 0);
        }
        float wb = Wb[ocol];
        #pragma unroll
        for (int r = 0; r < 4; ++r) {
            float v = acc[r] + wb;
            v = (v > 0.f) ? v : v * NEG_SLOPE;
            vout[ot][r] = v;
            sq[r] += v * v;
        }
    }
    #pragma unroll
    for (int r = 0; r < 4; ++r) {
        sq[r] += __shfl_xor(sq[r], 1);
        sq[r] += __shfl_xor(sq[r], 2);
        sq[r] += __shfl_xor(sq[r], 4);
        sq[r] += __shfl_xor(sq[r], 8);
    }
    if (lrow == 0) {
        #pragma unroll
        for (int r = 0; r < 4; ++r) s_part[wid][lk * 4 + r] = sq[r];
    }
    __syncthreads();
    if (tid < 16) {
        float s = s_part[0][tid] + s_part[1][tid] + s_part[2][tid] + s_part[3][tid];
        s_ninv[tid] = (s == 0.f) ? 1.f : 1.f / sqrtf(s);
    }
    __syncthreads();

    #pragma unroll
    for (int r = 0; r < 4; ++r) {
        int node = lk * 4 + r;
        int n = n0 + node;
        if (n < N) {
            float inv = s_ninv[node];
            #pragma unroll
            for (int ot = 0; ot < 4; ++ot)
                out[(long)n * O_DIM + wid * 64 + ot * 16 + lrow] = vout[ot][r] * inv;
        }
    }
}

extern "C" void kernel_launch(void* const* d_in, const int* in_sizes, int n_in,
                              void* d_out, int out_size, void* d_ws, size_t ws_size,
                              hipStream_t stream)
{
    const float* h        = (const float*)d_in[0];
    const int*   nodeset  = (const int*)  d_in[1];
    const int*   nb_nodes = (const int*)  d_in[2];
    const float* nb_w     = (const float*)d_in[3];
    const float* Qw       = (const float*)d_in[4];
    const float* Qb       = (const float*)d_in[5];
    const float* Ww       = (const float*)d_in[6];
    const float* Wb       = (const float*)d_in[7];
    float*       out      = (float*)d_out;

    int N = in_sizes[1];

    constexpr size_t QBYTES = (size_t)H_DIM * D_DIM * sizeof(ushort);   // 128 KB
    constexpr size_t WBYTES = (size_t)O_DIM * K2C * sizeof(ushort);     // 256 KB

    if (d_ws && ws_size >= QBYTES + WBYTES) {
        ushort* Qbf = (ushort*)d_ws;
        ushort* Wt  = (ushort*)((char*)d_ws + QBYTES);
        cvt_weights<<<(O_DIM * K2C + 255) / 256, 256, 0, stream>>>(Qw, Ww, Qbf, Wt);
        pinsage_fused<<<(N + NPB1 - 1) / NPB1, BLK1, 0, stream>>>(
            h, nodeset, nb_nodes, nb_w, Qbf, Qb, Wt, Wb, out, N);
    } else {
        pinsage_mono<<<(N + 15) / 16, 256, 0, stream>>>(
            h, nodeset, nb_nodes, nb_w, Qw, Qb, Ww, Wb, out, N);
    }
}